// Round 16
// baseline (185.406 us; speedup 1.0000x reference)
//
#include <hip/hip_runtime.h>
#include <hip/hip_bf16.h>

// EncoderBlock: B=2, N=4096, D=256, H=8, HD=32, DFF=1024.
// I/O fp32; internal bf16 MFMA.
// r21 (3rd submit; rounds 14-15 GPUAcquisitionTimeout — never ran).
// Base: r20 = 184.6us, absmax 0.03125. This round: raise GEMM residency.
// (a) gemm_wide: single-buffer LDS (32KB, r15's verified schedule) +
//     __launch_bounds__(256,4) -> 4 blocks/CU (was 2: 64KB dbuf + free VGPR).
//     r15/r16 showed dbuf==single at 2/CU; the win is the residency unlock.
// (b) gemm_epi: __launch_bounds__(256,3) (49.5KB LDS -> 3/CU; VGPR<=170).
// attn / wo_ln / p0 byte-identical to r20.
// Dead ends logged: MLP fusion (r18: 1 blk/CU), v_pk_fma asm (r16 NaN),
// magic-add pack (r13), Ps slot-XOR (r14 net-negative).
#define Bb 2
#define Nn 4096
#define Dd 256
#define Hh 8
#define HDh 32
#define DFFd 1024
#define MT (Bb*Nn)   // 8192 rows
#define Tt ((size_t)MT * Dd)
#define SPLIT 4
#define KVB (Nn / SPLIT)
#define NSTP (KVB / 64)   // 16

typedef __attribute__((ext_vector_type(8))) short short8;
typedef __attribute__((ext_vector_type(4))) float f32x4;
typedef __attribute__((address_space(1))) const unsigned int gu32;
typedef __attribute__((address_space(3))) unsigned int lu32;

__device__ __forceinline__ void gll16(const ushort* g, ushort* l) {
  // async global->LDS, 16B/lane; LDS dest = wave-uniform base + lane*16
  __builtin_amdgcn_global_load_lds((gu32*)g, (lu32*)l, 16, 0, 0);
}
__device__ __forceinline__ float bf2f(ushort u){
  union { unsigned int i; float f; } v; v.i = ((unsigned int)u) << 16; return v.f;
}
__device__ __forceinline__ ushort f2bf(float f){           // RNE
  union { float f; unsigned int i; } v; v.f = f;
  unsigned int r = v.i + 0x7fffu + ((v.i >> 16) & 1u);
  return (ushort)(r >> 16);
}
__device__ __forceinline__ int ars(int r){ return r * 64 + (r >> 3) * 32; }
__device__ __forceinline__ float gelu_f(float c){
  // gelu_tanh(c) = c*sigmoid(2y), y = 0.79788456(c+0.044715c^3); ~1ulp f32.
  const float u = c * c;
  const float s = __builtin_fmaf(0.044715f * u, c, c);
  const float m = __builtin_amdgcn_exp2f(-2.302144404f * s);
  return c * __builtin_amdgcn_rcpf(1.0f + m);
}

// ---- layernorm helper: 4 rows per wave --------------------------------------
__device__ __forceinline__ void ln_rows4(const float* __restrict__ x,
                                         ushort* __restrict__ out, int row0,
                                         int wave, int lane)
{
  #pragma unroll
  for (int r = 0; r < 4; r++) {
    const int row = row0 + wave * 4 + r;
    const float4 u = *(const float4*)(x + (size_t)row * Dd + lane * 4);
    float s1 = u.x + u.y + u.z + u.w;
    float s2 = u.x*u.x + u.y*u.y + u.z*u.z + u.w*u.w;
    #pragma unroll
    for (int m = 1; m < 64; m <<= 1) { s1 += __shfl_xor(s1, m, 64); s2 += __shfl_xor(s2, m, 64); }
    const float mean = s1 * (1.0f / Dd);
    float var = s2 * (1.0f / Dd) - mean * mean;
    var = var < 0.f ? 0.f : var;
    const float inv = 1.0f / (sqrtf(var) + 1e-6f);
    ushort4 o;
    o.x = f2bf((u.x - mean) * inv); o.y = f2bf((u.y - mean) * inv);
    o.z = f2bf((u.z - mean) * inv); o.w = f2bf((u.w - mean) * inv);
    *(ushort4*)(out + (size_t)row * Dd + lane * 4) = o;
  }
}

// ---- p0: weight transpose prep (blocks 0..192) + LN1 (all 512 blocks) ------
__global__ __launch_bounds__(256) void p0_kernel(
    const float* __restrict__ Wq, const float* __restrict__ Wk,
    const float* __restrict__ Wv, const float* __restrict__ Wo,
    const float* __restrict__ W1, const float* __restrict__ W2,
    const float* __restrict__ bq, const float* __restrict__ bk,
    const float* __restrict__ bv, ushort* __restrict__ wt,
    float* __restrict__ bqkv, const float* __restrict__ x,
    ushort* __restrict__ xn1)
{
  const int bid = blockIdx.x, t = threadIdx.x;
  __shared__ __align__(16) ushort T[64][72];
  if (bid < 192) {
    const float* src; ushort* dst; int Nsrc, Kdst, kt, nt;
    if (bid < 64) {
      const int m = bid >> 4, tile = bid & 15;
      kt = tile >> 2; nt = tile & 3; Nsrc = 256; Kdst = 256;
      src = (m == 0 ? Wq : m == 1 ? Wk : m == 2 ? Wv : Wo);
      dst = (m == 3) ? (wt + 196608) : (wt + m * 65536);
    } else if (bid < 128) {
      const int tile = bid - 64; kt = tile >> 4; nt = tile & 15;
      Nsrc = 1024; Kdst = 256; src = W1; dst = wt + 262144;
    } else {
      const int tile = bid - 128; kt = tile >> 2; nt = tile & 3;
      Nsrc = 256; Kdst = 1024; src = W2; dst = wt + 524288;
    }
    const int k0 = kt * 64, n0 = nt * 64;
    const int cc = t & 15, rr = t >> 4;
    #pragma unroll
    for (int pass = 0; pass < 4; pass++) {
      const int k = rr + pass * 16;
      const float4 v = *(const float4*)(src + (size_t)(k0 + k) * Nsrc + n0 + cc * 4);
      T[cc * 4 + 0][k] = f2bf(v.x); T[cc * 4 + 1][k] = f2bf(v.y);
      T[cc * 4 + 2][k] = f2bf(v.z); T[cc * 4 + 3][k] = f2bf(v.w);
    }
    __syncthreads();
    const int nl = t >> 2, ks = (t & 3) * 16;
    const short8 a = *(const short8*)(&T[nl][ks]);
    const short8 b = *(const short8*)(&T[nl][ks + 8]);
    ushort* drow = dst + (size_t)(n0 + nl) * Kdst + k0 + ks;
    *(short8*)(drow) = a; *(short8*)(drow + 8) = b;
  } else if (bid == 192) {
    bqkv[t] = bq[t]; bqkv[256 + t] = bk[t]; bqkv[512 + t] = bv[t];
  }
  ln_rows4(x, xn1, bid * 16, t >> 6, t & 63);
}

// ---- gemm_wide: 128x128 tile, 4 waves 2x2, per-wave 64x64 acc[4][4] --------
// r21: single-buffered 32KB LDS (r15 verified schedule) + launch_bounds(256,4)
// -> 4 blocks/CU. Chunk-XOR swizzle on unpadded 128B rows.
// EPI==2 (W1) writes hid split across two fragments (outv rows<2048, outv2
// rows>=2048); blocks never straddle (2048 % 128 == 0).
template<int EPI>
__global__ __launch_bounds__(256, 4) void gemm_wide(
    const ushort* __restrict__ A, const ushort* __restrict__ BT,
    const float* __restrict__ bias, void* __restrict__ outv, int N, int K,
    void* __restrict__ outv2)
{
  __shared__ __align__(16) ushort As[128 * 64];
  __shared__ __align__(16) ushort Bs[128 * 64];
  const int tid = threadIdx.x;
  const int wave = tid >> 6, lane = tid & 63;
  const int quad = lane >> 4, l15 = lane & 15;
  const int wm = wave >> 1, wn = wave & 1;
  const int n0 = blockIdx.x * 128, m0 = blockIdx.y * 128;
  f32x4 acc[4][4];
  #pragma unroll
  for (int mt = 0; mt < 4; mt++)
    #pragma unroll
    for (int nt = 0; nt < 4; nt++) acc[mt][nt] = (f32x4){0.f,0.f,0.f,0.f};
  const int srow = lane >> 3, scol = ((lane & 7) ^ srow) * 8;   // swizzled src chunk
  const ushort* gA[4];
  const ushort* gB[4];
  #pragma unroll
  for (int i = 0; i < 4; i++) {
    gA[i] = A  + (size_t)(m0 + i * 32 + wave * 8 + srow) * K + scol;
    gB[i] = BT + (size_t)(n0 + i * 32 + wave * 8 + srow) * K + scol;
  }
  int aoff[4], boff[4], cx[2];
  #pragma unroll
  for (int mt = 0; mt < 4; mt++) aoff[mt] = (wm * 64 + mt * 16 + l15) * 64;
  #pragma unroll
  for (int nt = 0; nt < 4; nt++) boff[nt] = (wn * 64 + nt * 16 + l15) * 64;
  #pragma unroll
  for (int kk = 0; kk < 2; kk++) cx[kk] = ((kk * 4 + quad) ^ (l15 & 7)) * 8;
  const int NC = K >> 6;
  for (int c = 0; c < NC; c++) {
    #pragma unroll
    for (int i = 0; i < 4; i++) {
      gll16(gA[i] + c * 64, &As[(i * 32 + wave * 8) * 64]);
      gll16(gB[i] + c * 64, &Bs[(i * 32 + wave * 8) * 64]);
    }
    __syncthreads();   // drains vmcnt: tile ready
    #pragma unroll
    for (int kk = 0; kk < 2; kk++) {
      short8 af[4];
      #pragma unroll
      for (int mt = 0; mt < 4; mt++)
        af[mt] = *(const short8*)(&As[aoff[mt] + cx[kk]]);
      #pragma unroll
      for (int nt = 0; nt < 4; nt++) {
        const short8 bf = *(const short8*)(&Bs[boff[nt] + cx[kk]]);
        #pragma unroll
        for (int mt = 0; mt < 4; mt++)
          acc[mt][nt] = __builtin_amdgcn_mfma_f32_16x16x32_bf16(af[mt], bf, acc[mt][nt], 0, 0, 0);
      }
    }
    __syncthreads();   // compute done: safe to overwrite tile
  }
  #pragma unroll
  for (int mt = 0; mt < 4; mt++) {
    const int row0 = m0 + wm * 64 + mt * 16 + quad * 4;
    #pragma unroll
    for (int nt = 0; nt < 4; nt++) {
      const int col = n0 + wn * 64 + nt * 16 + l15;
      const float bv = bias[col];
      float c[4];
      #pragma unroll
      for (int i = 0; i < 4; i++) c[i] = acc[mt][nt][i] + bv;
      if (EPI == 0) {
        ushort* qkv = (ushort*)outv;
        const int w = col >> 8, cd = col & 255;
        const int h = cd >> 5, hd = cd & 31;
        const int b = row0 >> 12, n = row0 & (Nn - 1);
        if (w < 2) {
          const float sc2 = (w == 0) ? (1.4426950408889634f * 0.17677669529663687f) : 1.0f;
          ushort* dst = qkv + (size_t)w * Tt + ((size_t)((b * Hh + h) * Nn) + n) * HDh + hd;
          #pragma unroll
          for (int i = 0; i < 4; i++) dst[(size_t)i * HDh] = f2bf(c[i] * sc2);
        } else {   // V transposed: [b,h,hd,n]
          ushort4 pk;
          pk.x = f2bf(c[0]); pk.y = f2bf(c[1]); pk.z = f2bf(c[2]); pk.w = f2bf(c[3]);
          *(ushort4*)(qkv + 2 * Tt + ((size_t)((b * Hh + h) * HDh + hd)) * Nn + n) = pk;
        }
      } else {   // EPI==2: fast gelu -> bf16, two-fragment hid
        ushort* ob = (m0 < 2048) ? (ushort*)outv
                                 : (ushort*)outv2 - (size_t)2048 * N;
        #pragma unroll
        for (int i = 0; i < 4; i++)
          ob[(size_t)(row0 + i) * N + col] = f2bf(gelu_f(c[i]));
      }
    }
  }
}

// ---- wo_ln: fused attn-combine + Wo GEMM + residual + LN2 ------------------
// Grid 256, BM=32 rows/block, full N=256 (wave w owns cols w*64..w*64+63).
// A = combine(op0..op3)/l  (reg-staged, bit-identical order to old combine),
// staged to LDS with the chunk-XOR involution. B = wtO via gll16. Epilogue:
// v = acc + bo + x  -> xsk (fp32) ; row mean/var via shuffle+LDS -> xn2 bf16.
__global__ __launch_bounds__(256) void wo_ln(
    const ushort* __restrict__ op0, const ushort* __restrict__ op123,
    const float* __restrict__ lp, const ushort* __restrict__ BT,
    const float* __restrict__ bo, const float* __restrict__ x,
    float* __restrict__ xsk, ushort* __restrict__ xn2)
{
  __shared__ __align__(16) ushort As[2][32 * 64];
  __shared__ __align__(16) ushort Bs[2][256 * 64];
  __shared__ float Linv[32][8];
  __shared__ float RS[2][4][32];
  __shared__ float MN[32][2];
  const int tid = threadIdx.x;
  const int wave = tid >> 6, lane = tid & 63;
  const int quad = lane >> 4, l15 = lane & 15;
  const int m0 = blockIdx.x * 32;
  const int srow = lane >> 3, scol = ((lane & 7) ^ srow) * 8;
  int cx[2];
  #pragma unroll
  for (int kk = 0; kk < 2; kk++) cx[kk] = ((kk * 4 + quad) ^ (l15 & 7)) * 8;
  const size_t SPS = (size_t)16 * Nn * HDh;          // op-part stride (ushorts)
  // ---- Linv[r][h] = 1/sum_sp l ----
  {
    const int r = tid >> 3, h = tid & 7;
    const int row = m0 + r;
    const size_t li = (size_t)((row >> 12) * Hh + h) * Nn + (row & (Nn - 1));
    float l = 0.f;
    #pragma unroll
    for (int sp = 0; sp < SPLIT; sp++) l += lp[sp * (16 * Nn) + li];
    Linv[r][h] = 1.0f / l;
  }
  // staging lane mapping for A: r=tid>>3 (row), e=tid&7 (8-elem chunk)
  const int ar = tid >> 3, ae = tid & 7;
  const int ah2 = ae >> 2, ahd0 = (ae & 3) * 8;
  const int arow = m0 + ar;
  const size_t abase = ((size_t)((arow >> 12) * Hh) * Nn + (arow & (Nn - 1))) * HDh + ahd0;
  short8 a0, a1, a2, a3;
  #define LOADA(cs) { \
    const size_t off = abase + (size_t)((cs) * 2 + ah2) * (Nn * HDh); \
    a0 = *(const short8*)(op0 + off); \
    a1 = *(const short8*)(op123 + off); \
    a2 = *(const short8*)(op123 + SPS + off); \
    a3 = *(const short8*)(op123 + 2 * SPS + off); }
  #define WRITEA(q, cs) { \
    const float inv = Linv[ar][(cs) * 2 + ah2]; \
    short8 w; \
    _Pragma("unroll") \
    for (int j = 0; j < 8; j++) { \
      const float sum = ((bf2f((ushort)a0[j]) + bf2f((ushort)a1[j])) \
                        + bf2f((ushort)a2[j])) + bf2f((ushort)a3[j]); \
      w[j] = (short)f2bf(sum * inv); } \
    *(short8*)(&As[q][ar * 64 + (ae ^ (ar & 7)) * 8]) = w; }
  #define STAGEB(cs, q) { \
    _Pragma("unroll") \
    for (int i = 0; i < 8; i++) \
      gll16(BT + (size_t)(wave * 64 + i * 8 + srow) * 256 + (cs) * 64 + scol, \
            &Bs[q][(wave * 64 + i * 8) * 64]); }
  LOADA(0);
  STAGEB(0, 0);
  __syncthreads();          // Linv visible; Bs[0] drained
  WRITEA(0, 0);
  __syncthreads();          // As[0] ready
  f32x4 acc[2][4];
  #pragma unroll
  for (int mt = 0; mt < 2; mt++)
    #pragma unroll
    for (int nt = 0; nt < 4; nt++) acc[mt][nt] = (f32x4){0.f,0.f,0.f,0.f};
  int p = 0;
  #pragma unroll
  for (int cs = 0; cs < 4; cs++) {
    if (cs < 3) { LOADA(cs + 1); STAGEB(cs + 1, p ^ 1); }
    #pragma unroll
    for (int kk = 0; kk < 2; kk++) {
      short8 af[2];
      #pragma unroll
      for (int mt = 0; mt < 2; mt++)
        af[mt] = *(const short8*)(&As[p][(mt * 16 + l15) * 64 + cx[kk]]);
      #pragma unroll
      for (int nt = 0; nt < 4; nt++) {
        const short8 bf = *(const short8*)(&Bs[p][(wave * 64 + nt * 16 + l15) * 64 + cx[kk]]);
        #pragma unroll
        for (int mt = 0; mt < 2; mt++)
          acc[mt][nt] = __builtin_amdgcn_mfma_f32_16x16x32_bf16(af[mt], bf, acc[mt][nt], 0, 0, 0);
      }
    }
    if (cs < 3) WRITEA(p ^ 1, cs + 1);
    __syncthreads();
    p ^= 1;
  }
  // ---- epilogue: v = acc + bo + x ; xsk ; LN -> xn2 ----
  float v[2][4][4];
  float s1[2][4], s2[2][4];
  #pragma unroll
  for (int mt = 0; mt < 2; mt++)
    #pragma unroll
    for (int i = 0; i < 4; i++) { s1[mt][i] = 0.f; s2[mt][i] = 0.f; }
  #pragma unroll
  for (int mt = 0; mt < 2; mt++) {
    const int row0 = m0 + mt * 16 + quad * 4;
    #pragma unroll
    for (int nt = 0; nt < 4; nt++) {
      const int col = wave * 64 + nt * 16 + l15;
      const float bv = bo[col];
      #pragma unroll
      for (int i = 0; i < 4; i++) {
        const size_t idx = (size_t)(row0 + i) * Dd + col;
        const float t = (acc[mt][nt][i] + bv) + x[idx];
        v[mt][nt][i] = t;
        xsk[idx] = t;
        s1[mt][i] += t;
        s2[mt][i] += t * t;
      }
    }
  }
  #pragma unroll
  for (int mt = 0; mt < 2; mt++)
    #pragma unroll
    for (int i = 0; i < 4; i++)
      #pragma unroll
      for (int m = 1; m < 16; m <<= 1) {
        s1[mt][i] += __shfl_xor(s1[mt][i], m, 64);
        s2[mt][i] += __shfl_xor(s2[mt][i], m, 64);
      }
  if (l15 == 0) {
    #pragma unroll
    for (int mt = 0; mt < 2; mt++)
      #pragma unroll
      for (int i = 0; i < 4; i++) {
        const int r = mt * 16 + quad * 4 + i;
        RS[0][wave][r] = s1[mt][i];
        RS[1][wave][r] = s2[mt][i];
      }
  }
  __syncthreads();
  if (tid < 32) {
    const float t1 = RS[0][0][tid] + RS[0][1][tid] + RS[0][2][tid] + RS[0][3][tid];
    const float t2 = RS[1][0][tid] + RS[1][1][tid] + RS[1][2][tid] + RS[1][3][tid];
    const float mean = t1 * (1.0f / Dd);
    float var = t2 * (1.0f / Dd) - mean * mean;
    var = var < 0.f ? 0.f : var;
    MN[tid][0] = mean;
    MN[tid][1] = 1.0f / (sqrtf(var) + 1e-6f);
  }
  __syncthreads();
  #pragma unroll
  for (int mt = 0; mt < 2; mt++) {
    const int row0 = m0 + mt * 16 + quad * 4;
    #pragma unroll
    for (int i = 0; i < 4; i++) {
      const int r = mt * 16 + quad * 4 + i;
      const float mean = MN[r][0], inv = MN[r][1];
      #pragma unroll
      for (int nt = 0; nt < 4; nt++) {
        const int col = wave * 64 + nt * 16 + l15;
        xn2[(size_t)(row0 + i) * Dd + col] = f2bf((v[mt][nt][i] - mean) * inv);
      }
    }
  }
  #undef LOADA
  #undef WRITEA
  #undef STAGEB
}

// ---- BMx64-tile MFMA GEMM (W2 only): BK=64 gll16 double-buffer -------------
// A read from two hid fragments (A rows<2048, A2 rows>=2048; blocks never
// straddle since 2048 % BM == 0). r12 chunk-XOR swizzle on As/Bs.
// r21: launch_bounds(256,3) (49.5KB LDS -> 3 blocks/CU; VGPR <= 170).
template<int EPI, int BM>
__global__ __launch_bounds__(256, 3) void gemm_epi(
    const ushort* __restrict__ A, const ushort* __restrict__ A2,
    const ushort* __restrict__ BT,
    const float* __restrict__ bias, const float* __restrict__ res,
    void* __restrict__ outv, int N, int K)
{
  constexpr int MI = BM / 64;
  constexpr int AI = BM / 32;
  __shared__ __align__(16) ushort AsF[2][BM * 64 + (BM / 8) * 32];
  __shared__ __align__(16) ushort BsF[2][64 * 64 + 8 * 32];
  const int tid = threadIdx.x;
  const int wave = tid >> 6, lane = tid & 63;
  const int quad = lane >> 4, l15 = lane & 15;
  const int n0 = blockIdx.x * 64, m0 = blockIdx.y * BM;
  const ushort* Abase = (m0 < 2048) ? A : A2 - (size_t)2048 * K;
  f32x4 acc[MI][4];
  #pragma unroll
  for (int mt = 0; mt < MI; mt++)
    #pragma unroll
    for (int nt = 0; nt < 4; nt++) acc[mt][nt] = (f32x4){0.f,0.f,0.f,0.f};
  const int srow = lane >> 3, scol = ((lane & 7) ^ srow) * 8;   // swizzled src chunk
  const ushort* gA[AI];
  #pragma unroll
  for (int ai = 0; ai < AI; ai++)
    gA[ai] = Abase + (size_t)(m0 + ai * 32 + wave * 8 + srow) * K + scol;
  const ushort* gB[2];
  #pragma unroll
  for (int bi = 0; bi < 2; bi++)
    gB[bi] = BT + (size_t)(n0 + bi * 32 + wave * 8 + srow) * K + scol;
  int aoff[MI], boff[4];
  #pragma unroll
  for (int mt = 0; mt < MI; mt++) aoff[mt] = ars(wave * 16 * MI + mt * 16 + l15);
  #pragma unroll
  for (int nt = 0; nt < 4; nt++) boff[nt] = ars(nt * 16 + l15);
  int cx[2];
  #pragma unroll
  for (int kk = 0; kk < 2; kk++) cx[kk] = ((kk * 4 + quad) ^ (l15 & 7)) * 8;
  #pragma unroll
  for (int ai = 0; ai < AI; ai++) gll16(gA[ai], &AsF[0][ars(ai * 32 + wave * 8)]);
  #pragma unroll
  for (int bi = 0; bi < 2; bi++) gll16(gB[bi], &BsF[0][ars(bi * 32 + wave * 8)]);
  __syncthreads();
  const int NC = K >> 6;
  int p = 0;
  for (int c = 0; c < NC; c++) {
    if (c + 1 < NC) {
      #pragma unroll
      for (int ai = 0; ai < AI; ai++)
        gll16(gA[ai] + (c + 1) * 64, &AsF[p ^ 1][ars(ai * 32 + wave * 8)]);
      #pragma unroll
      for (int bi = 0; bi < 2; bi++)
        gll16(gB[bi] + (c + 1) * 64, &BsF[p ^ 1][ars(bi * 32 + wave * 8)]);
    }
    #pragma unroll
    for (int kk = 0; kk < 2; kk++) {
      short8 af[MI];
      #pragma unroll
      for (int mt = 0; mt < MI; mt++)
        af[mt] = *(const short8*)(&AsF[p][aoff[mt] + cx[kk]]);
      #pragma unroll
      for (int nt = 0; nt < 4; nt++) {
        const short8 bf = *(const short8*)(&BsF[p][boff[nt] + cx[kk]]);
        #pragma unroll
        for (int mt = 0; mt < MI; mt++)
          acc[mt][nt] = __builtin_amdgcn_mfma_f32_16x16x32_bf16(af[mt], bf, acc[mt][nt], 0, 0, 0);
      }
    }
    __syncthreads();
    p ^= 1;
  }
  #pragma unroll
  for (int mt = 0; mt < MI; mt++) {
    const int row0 = m0 + wave * (16 * MI) + mt * 16 + quad * 4;
    #pragma unroll
    for (int nt = 0; nt < 4; nt++) {
      const int col = n0 + nt * 16 + l15;
      const float bv = bias[col];
      float c[4];
      #pragma unroll
      for (int i = 0; i < 4; i++) c[i] = acc[mt][nt][i] + bv;
      if (EPI == 1) {
        float* out = (float*)outv;
        #pragma unroll
        for (int i = 0; i < 4; i++) {
          const size_t idx = (size_t)(row0 + i) * N + col;
          out[idx] = c[i] + res[idx];
        }
      } else {
        ushort* out = (ushort*)outv;
        #pragma unroll
        for (int i = 0; i < 4; i++)
          out[(size_t)(row0 + i) * N + col] = f2bf(gelu_f(c[i]));
      }
    }
  }
}

// ---- Flash attention: split-K(4), q=64/wave, bf16 partial O + fp32 l -------
// r12 version (measured ~54-56us, absmax 0.03125). Schraudolph exp2 softmax;
// self-normalizing l. Ks chunk-XOR swizzle; Ps/Vt plain.
__global__ __launch_bounds__(256, 4) void attn_kernel(
    const ushort* __restrict__ qp, const ushort* __restrict__ kp,
    const ushort* __restrict__ vtg, ushort* __restrict__ op0,
    ushort* __restrict__ op123, float* __restrict__ lp)
{
  __shared__ __align__(16) ushort Ks[2][64][32];   // K tile [kv][d] (gll16, chunk-swz)
  __shared__ __align__(16) ushort Vt[2][32][72];   // V^T tile [d][kv] (reg-staged)
  __shared__ __align__(16) ushort Ps[4][64][40];   // per-wave P [q][kv-half]
  const int tid = threadIdx.x;
  const int wave = tid >> 6, lane = tid & 63;
  const int quad = lane >> 4, l15 = lane & 15;
  const int qtb = blockIdx.x, bh = blockIdx.y, sp = blockIdx.z;
  const size_t base = (size_t)bh * Nn * HDh;
  const int q0 = qtb * 256 + wave * 64;
  short8 qf[4];
  #pragma unroll
  for (int qt = 0; qt < 4; qt++)
    qf[qt] = *(const short8*)(qp + base + (size_t)(q0 + qt * 16 + l15) * HDh + quad * 8);
  const int kv0 = sp * KVB;
  const ushort* kg = kp + base + (size_t)(kv0 + wave * 16 + (lane >> 2)) * HDh
                   + (((lane & 3) ^ ((lane >> 3) & 3)) * 8);   // swizzled src chunk
  const int kc = (quad ^ ((l15 >> 1) & 3)) * 8;                // swizzled read chunk
  const int vr = tid >> 3, vc = (tid & 7) * 8;
  const ushort* vg = vtg + base + (size_t)vr * Nn + kv0 + vc;
  ushort* psw = &Ps[wave][0][0];
  f32x4 o[2][4], ol[4];
  #pragma unroll
  for (int qt = 0; qt < 4; qt++) {
    o[0][qt] = (f32x4){0,0,0,0}; o[1][qt] = (f32x4){0,0,0,0};
    ol[qt] = (f32x4){0,0,0,0};
  }
  const short one = (short)0x3F80;
  const short8 ones = {one,one,one,one,one,one,one,one};
  const f32x4 zero4 = {0,0,0,0};
  const float SA = 8388608.0f;        // 2^23
  const float SB = 1065102389.0f;     // (127<<23) - minimax bias (~3% two-sided)
  gll16(kg, &Ks[0][wave * 16][0]);
  int4 vreg = *(const int4*)vg;
  *(int4*)(&Vt[0][vr][vc]) = vreg;
  vreg = *(const int4*)(vg + 64);
  __syncthreads();
  #pragma unroll 2
  for (int step = 0; step < NSTP; step++) {
    const int p = step & 1;
    if (step + 1 < NSTP) {
      gll16(kg + (size_t)(step + 1) * 64 * HDh, &Ks[p ^ 1][wave * 16][0]);
      *(int4*)(&Vt[p ^ 1][vr][vc]) = vreg;
    }
    if (step + 2 < NSTP) vreg = *(const int4*)(vg + (size_t)(step + 2) * 64);
    #pragma unroll
    for (int half = 0; half < 2; half++) {
      #pragma unroll
      for (int nt2 = 0; nt2 < 2; nt2++) {
        const int nt = half * 2 + nt2;
        const short8 kf = *(const short8*)(&Ks[p][nt * 16 + l15][kc]);
        #pragma unroll
        for (int qt = 0; qt < 4; qt++) {
          const f32x4 s = __builtin_amdgcn_mfma_f32_16x16x32_bf16(kf, qf[qt], zero4, 0, 0, 0);
          const unsigned int i0 = (unsigned int)(int)fmaf(s[0], SA, SB);
          const unsigned int i1 = (unsigned int)(int)fmaf(s[1], SA, SB);
          const unsigned int i2 = (unsigned int)(int)fmaf(s[2], SA, SB);
          const unsigned int i3 = (unsigned int)(int)fmaf(s[3], SA, SB);
          uint2 pk;
          pk.x = __builtin_amdgcn_perm(i1, i0, 0x07060302u);
          pk.y = __builtin_amdgcn_perm(i3, i2, 0x07060302u);
          *(uint2*)(psw + (qt * 16 + l15) * 40 + nt2 * 16 + quad * 4) = pk;
        }
      }
      __builtin_amdgcn_wave_barrier();   // Ps wave-local; DS in-order per wave
      const short8 v0 = *(const short8*)(&Vt[p][l15][half * 32 + quad * 8]);
      const short8 v1 = *(const short8*)(&Vt[p][16 + l15][half * 32 + quad * 8]);
      #pragma unroll
      for (int qt = 0; qt < 4; qt++) {
        const short8 pb = *(const short8*)(psw + (qt * 16 + l15) * 40 + quad * 8);
        o[0][qt] = __builtin_amdgcn_mfma_f32_16x16x32_bf16(v0, pb, o[0][qt], 0, 0, 0);
        o[1][qt] = __builtin_amdgcn_mfma_f32_16x16x32_bf16(v1, pb, o[1][qt], 0, 0, 0);
        ol[qt]   = __builtin_amdgcn_mfma_f32_16x16x32_bf16(ones, pb, ol[qt], 0, 0, 0);
      }
      __builtin_amdgcn_wave_barrier();
    }
    __syncthreads();   // drains this step's prefetches (full phase elapsed)
  }
  lp[(size_t)sp * (16 * Nn) + (size_t)bh * Nn + q0 + lane] = ol[lane >> 4][0];
  ushort* ob = (sp == 0 ? op0 : op123 + (size_t)(sp - 1) * (16 * (size_t)Nn * HDh));
  #pragma unroll
  for (int pass = 0; pass < 2; pass++) {
    #pragma unroll
    for (int qt2 = 0; qt2 < 2; qt2++) {
      const int qt = pass * 2 + qt2;
      #pragma unroll
      for (int dt = 0; dt < 2; dt++) {
        ushort4 pk;
        pk.x = f2bf(o[dt][qt][0]); pk.y = f2bf(o[dt][qt][1]);
        pk.z = f2bf(o[dt][qt][2]); pk.w = f2bf(o[dt][qt][3]);
        *(ushort4*)(psw + (qt2 * 16 + l15) * 40 + dt * 16 + quad * 4) = pk;
      }
    }
    __builtin_amdgcn_wave_barrier();
    #pragma unroll
    for (int j = 0; j < 2; j++) {
      const int row = j * 16 + (lane >> 2);
      const short8 ov = *(const short8*)(psw + row * 40 + (lane & 3) * 8);
      const int q = q0 + pass * 32 + row;
      *(short8*)(ob + ((size_t)bh * Nn + q) * HDh + (lane & 3) * 8) = ov;
    }
    __builtin_amdgcn_wave_barrier();
  }
}

extern "C" void kernel_launch(void* const* d_in, const int* in_sizes, int n_in,
                              void* d_out, int out_size, void* d_ws, size_t ws_size,
                              hipStream_t stream)
{
  const float* x  = (const float*)d_in[0];
  const float* Wq = (const float*)d_in[1];
  const float* bq = (const float*)d_in[2];
  const float* Wk = (const float*)d_in[3];
  const float* bk = (const float*)d_in[4];
  const float* Wv = (const float*)d_in[5];
  const float* bv = (const float*)d_in[6];
  const float* Wo = (const float*)d_in[7];
  const float* bo = (const float*)d_in[8];
  const float* W1 = (const float*)d_in[9];
  const float* b1 = (const float*)d_in[10];
  const float* W2 = (const float*)d_in[11];
  const float* b2 = (const float*)d_in[12];

  char* ws = (char*)d_ws;
  ushort* wt    = (ushort*)ws;                       // 786432 bf16
  ushort* wtqkv = wt;
  ushort* wto   = wt + 196608;
  ushort* wt1   = wt + 262144;
  ushort* wt2   = wt + 524288;
  float*  bqkv  = (float*)(ws + 786432 * 2);
  ushort* s0    = (ushort*)(ws + 786432 * 2 + 4096); // 4 MiB slots
  ushort* s1    = s0 + Tt;                           // q (dead after attn)
  ushort* s2    = s1 + Tt;                           // k (dead after attn)
  ushort* s3    = s2 + Tt;                           // v^T (dead after attn)
  ushort* oxsk  = s3 + Tt;                           // old-xsk region (8 MiB)
  ushort* xn1   = s0;
  ushort* op0   = s0;                                // attn partial sp0 (xn1 dead)
  ushort* op123 = oxsk;                              // sp1..sp3 (12 MiB: oxsk+old-xn2)
  float*  xskN  = (float*)s1;                        // fp32 8 MiB (s1+s2)
  ushort* xn2N  = s3;                                // bf16 4 MiB
  ushort* hid1  = s0;                                // hid rows 0..2047
  ushort* hid2  = oxsk;                              // hid rows 2048..8191 (12 MiB)
  float*  lp    = (float*)d_out;                     // scratch in d_out
  float*  outp  = (float*)d_out;

  const dim3 blk(256);
  hipLaunchKernelGGL(p0_kernel, dim3(512), blk, 0, stream,
                     Wq, Wk, Wv, Wo, W1, W2, bq, bk, bv, wt, bqkv, x, xn1);
  hipLaunchKernelGGL((gemm_wide<0>), dim3(6, 64), blk, 0, stream,
                     xn1, wtqkv, bqkv, (void*)s1, 768, Dd, (void*)nullptr);

  hipLaunchKernelGGL(attn_kernel, dim3(Nn / 256, Bb * Hh, SPLIT), blk, 0, stream,
                     s1, s2, s3, op0, op123, lp);

  hipLaunchKernelGGL(wo_ln, dim3(MT / 32), blk, 0, stream,
                     op0, op123, lp, wto, bo, x, xskN, xn2N);

  hipLaunchKernelGGL((gemm_wide<2>), dim3(8, 64), blk, 0, stream,
                     xn2N, wt1, b1, (void*)hid1, DFFd, Dd, (void*)hid2);
  hipLaunchKernelGGL((gemm_epi<1,128>), dim3(4, 64), blk, 0, stream,
                     hid1, hid2, wt2, b2, xskN, (void*)outp, Dd, DFFd);
}

// Round 17
// 182.371 us; speedup vs baseline: 1.0166x; 1.0166x over previous
//
#include <hip/hip_runtime.h>
#include <hip/hip_bf16.h>

// EncoderBlock: B=2, N=4096, D=256, H=8, HD=32, DFF=1024.
// I/O fp32; internal bf16 MFMA.
// r22 (base: r21 = 185.4us ~ r20 = 184.6us, absmax 0.03125).
// r21 post-mortem: 2->4 blocks/CU on gemm_wide = null. But TWO kernels sit at
// exactly 1 block/CU — the r18 disaster regime (gemm_mlp: 62us, 10% occ):
// (a) W2 was gemm_epi<1,128> grid (4,64)=256 blocks=1/CU (my r19 change,
//     never isolated). Revert to BM=64 grid (4,128)=512=2/CU (r12-verified).
// (b) wo_ln was grid 256=1/CU. Now BM=16, grid 512=2/CU (A-staging/Linv on
//     tid<128, acc[4], 16-row LN reduce; LDS 69KB). Same K-order per output.
// Dead ends logged: MLP fusion (r18), v_pk_fma asm (r16 NaN), magic-add
// pack (r13), Ps slot-XOR (r14), residency at 2->4 margin (r21 null).
#define Bb 2
#define Nn 4096
#define Dd 256
#define Hh 8
#define HDh 32
#define DFFd 1024
#define MT (Bb*Nn)   // 8192 rows
#define Tt ((size_t)MT * Dd)
#define SPLIT 4
#define KVB (Nn / SPLIT)
#define NSTP (KVB / 64)   // 16

typedef __attribute__((ext_vector_type(8))) short short8;
typedef __attribute__((ext_vector_type(4))) float f32x4;
typedef __attribute__((address_space(1))) const unsigned int gu32;
typedef __attribute__((address_space(3))) unsigned int lu32;

__device__ __forceinline__ void gll16(const ushort* g, ushort* l) {
  // async global->LDS, 16B/lane; LDS dest = wave-uniform base + lane*16
  __builtin_amdgcn_global_load_lds((gu32*)g, (lu32*)l, 16, 0, 0);
}
__device__ __forceinline__ float bf2f(ushort u){
  union { unsigned int i; float f; } v; v.i = ((unsigned int)u) << 16; return v.f;
}
__device__ __forceinline__ ushort f2bf(float f){           // RNE
  union { float f; unsigned int i; } v; v.f = f;
  unsigned int r = v.i + 0x7fffu + ((v.i >> 16) & 1u);
  return (ushort)(r >> 16);
}
__device__ __forceinline__ int ars(int r){ return r * 64 + (r >> 3) * 32; }
__device__ __forceinline__ float gelu_f(float c){
  // gelu_tanh(c) = c*sigmoid(2y), y = 0.79788456(c+0.044715c^3); ~1ulp f32.
  const float u = c * c;
  const float s = __builtin_fmaf(0.044715f * u, c, c);
  const float m = __builtin_amdgcn_exp2f(-2.302144404f * s);
  return c * __builtin_amdgcn_rcpf(1.0f + m);
}

// ---- layernorm helper: 4 rows per wave --------------------------------------
__device__ __forceinline__ void ln_rows4(const float* __restrict__ x,
                                         ushort* __restrict__ out, int row0,
                                         int wave, int lane)
{
  #pragma unroll
  for (int r = 0; r < 4; r++) {
    const int row = row0 + wave * 4 + r;
    const float4 u = *(const float4*)(x + (size_t)row * Dd + lane * 4);
    float s1 = u.x + u.y + u.z + u.w;
    float s2 = u.x*u.x + u.y*u.y + u.z*u.z + u.w*u.w;
    #pragma unroll
    for (int m = 1; m < 64; m <<= 1) { s1 += __shfl_xor(s1, m, 64); s2 += __shfl_xor(s2, m, 64); }
    const float mean = s1 * (1.0f / Dd);
    float var = s2 * (1.0f / Dd) - mean * mean;
    var = var < 0.f ? 0.f : var;
    const float inv = 1.0f / (sqrtf(var) + 1e-6f);
    ushort4 o;
    o.x = f2bf((u.x - mean) * inv); o.y = f2bf((u.y - mean) * inv);
    o.z = f2bf((u.z - mean) * inv); o.w = f2bf((u.w - mean) * inv);
    *(ushort4*)(out + (size_t)row * Dd + lane * 4) = o;
  }
}

// ---- p0: weight transpose prep (blocks 0..192) + LN1 (all 512 blocks) ------
__global__ __launch_bounds__(256) void p0_kernel(
    const float* __restrict__ Wq, const float* __restrict__ Wk,
    const float* __restrict__ Wv, const float* __restrict__ Wo,
    const float* __restrict__ W1, const float* __restrict__ W2,
    const float* __restrict__ bq, const float* __restrict__ bk,
    const float* __restrict__ bv, ushort* __restrict__ wt,
    float* __restrict__ bqkv, const float* __restrict__ x,
    ushort* __restrict__ xn1)
{
  const int bid = blockIdx.x, t = threadIdx.x;
  __shared__ __align__(16) ushort T[64][72];
  if (bid < 192) {
    const float* src; ushort* dst; int Nsrc, Kdst, kt, nt;
    if (bid < 64) {
      const int m = bid >> 4, tile = bid & 15;
      kt = tile >> 2; nt = tile & 3; Nsrc = 256; Kdst = 256;
      src = (m == 0 ? Wq : m == 1 ? Wk : m == 2 ? Wv : Wo);
      dst = (m == 3) ? (wt + 196608) : (wt + m * 65536);
    } else if (bid < 128) {
      const int tile = bid - 64; kt = tile >> 4; nt = tile & 15;
      Nsrc = 1024; Kdst = 256; src = W1; dst = wt + 262144;
    } else {
      const int tile = bid - 128; kt = tile >> 2; nt = tile & 3;
      Nsrc = 256; Kdst = 1024; src = W2; dst = wt + 524288;
    }
    const int k0 = kt * 64, n0 = nt * 64;
    const int cc = t & 15, rr = t >> 4;
    #pragma unroll
    for (int pass = 0; pass < 4; pass++) {
      const int k = rr + pass * 16;
      const float4 v = *(const float4*)(src + (size_t)(k0 + k) * Nsrc + n0 + cc * 4);
      T[cc * 4 + 0][k] = f2bf(v.x); T[cc * 4 + 1][k] = f2bf(v.y);
      T[cc * 4 + 2][k] = f2bf(v.z); T[cc * 4 + 3][k] = f2bf(v.w);
    }
    __syncthreads();
    const int nl = t >> 2, ks = (t & 3) * 16;
    const short8 a = *(const short8*)(&T[nl][ks]);
    const short8 b = *(const short8*)(&T[nl][ks + 8]);
    ushort* drow = dst + (size_t)(n0 + nl) * Kdst + k0 + ks;
    *(short8*)(drow) = a; *(short8*)(drow + 8) = b;
  } else if (bid == 192) {
    bqkv[t] = bq[t]; bqkv[256 + t] = bk[t]; bqkv[512 + t] = bv[t];
  }
  ln_rows4(x, xn1, bid * 16, t >> 6, t & 63);
}

// ---- gemm_wide: 128x128 tile, 4 waves 2x2, per-wave 64x64 acc[4][4] --------
// Single-buffered 32KB LDS + launch_bounds(256,4). Chunk-XOR swizzle.
// EPI==2 (W1) writes hid split across two fragments (outv rows<2048, outv2
// rows>=2048); blocks never straddle (2048 % 128 == 0).
template<int EPI>
__global__ __launch_bounds__(256, 4) void gemm_wide(
    const ushort* __restrict__ A, const ushort* __restrict__ BT,
    const float* __restrict__ bias, void* __restrict__ outv, int N, int K,
    void* __restrict__ outv2)
{
  __shared__ __align__(16) ushort As[128 * 64];
  __shared__ __align__(16) ushort Bs[128 * 64];
  const int tid = threadIdx.x;
  const int wave = tid >> 6, lane = tid & 63;
  const int quad = lane >> 4, l15 = lane & 15;
  const int wm = wave >> 1, wn = wave & 1;
  const int n0 = blockIdx.x * 128, m0 = blockIdx.y * 128;
  f32x4 acc[4][4];
  #pragma unroll
  for (int mt = 0; mt < 4; mt++)
    #pragma unroll
    for (int nt = 0; nt < 4; nt++) acc[mt][nt] = (f32x4){0.f,0.f,0.f,0.f};
  const int srow = lane >> 3, scol = ((lane & 7) ^ srow) * 8;   // swizzled src chunk
  const ushort* gA[4];
  const ushort* gB[4];
  #pragma unroll
  for (int i = 0; i < 4; i++) {
    gA[i] = A  + (size_t)(m0 + i * 32 + wave * 8 + srow) * K + scol;
    gB[i] = BT + (size_t)(n0 + i * 32 + wave * 8 + srow) * K + scol;
  }
  int aoff[4], boff[4], cx[2];
  #pragma unroll
  for (int mt = 0; mt < 4; mt++) aoff[mt] = (wm * 64 + mt * 16 + l15) * 64;
  #pragma unroll
  for (int nt = 0; nt < 4; nt++) boff[nt] = (wn * 64 + nt * 16 + l15) * 64;
  #pragma unroll
  for (int kk = 0; kk < 2; kk++) cx[kk] = ((kk * 4 + quad) ^ (l15 & 7)) * 8;
  const int NC = K >> 6;
  for (int c = 0; c < NC; c++) {
    #pragma unroll
    for (int i = 0; i < 4; i++) {
      gll16(gA[i] + c * 64, &As[(i * 32 + wave * 8) * 64]);
      gll16(gB[i] + c * 64, &Bs[(i * 32 + wave * 8) * 64]);
    }
    __syncthreads();   // drains vmcnt: tile ready
    #pragma unroll
    for (int kk = 0; kk < 2; kk++) {
      short8 af[4];
      #pragma unroll
      for (int mt = 0; mt < 4; mt++)
        af[mt] = *(const short8*)(&As[aoff[mt] + cx[kk]]);
      #pragma unroll
      for (int nt = 0; nt < 4; nt++) {
        const short8 bf = *(const short8*)(&Bs[boff[nt] + cx[kk]]);
        #pragma unroll
        for (int mt = 0; mt < 4; mt++)
          acc[mt][nt] = __builtin_amdgcn_mfma_f32_16x16x32_bf16(af[mt], bf, acc[mt][nt], 0, 0, 0);
      }
    }
    __syncthreads();   // compute done: safe to overwrite tile
  }
  #pragma unroll
  for (int mt = 0; mt < 4; mt++) {
    const int row0 = m0 + wm * 64 + mt * 16 + quad * 4;
    #pragma unroll
    for (int nt = 0; nt < 4; nt++) {
      const int col = n0 + wn * 64 + nt * 16 + l15;
      const float bv = bias[col];
      float c[4];
      #pragma unroll
      for (int i = 0; i < 4; i++) c[i] = acc[mt][nt][i] + bv;
      if (EPI == 0) {
        ushort* qkv = (ushort*)outv;
        const int w = col >> 8, cd = col & 255;
        const int h = cd >> 5, hd = cd & 31;
        const int b = row0 >> 12, n = row0 & (Nn - 1);
        if (w < 2) {
          const float sc2 = (w == 0) ? (1.4426950408889634f * 0.17677669529663687f) : 1.0f;
          ushort* dst = qkv + (size_t)w * Tt + ((size_t)((b * Hh + h) * Nn) + n) * HDh + hd;
          #pragma unroll
          for (int i = 0; i < 4; i++) dst[(size_t)i * HDh] = f2bf(c[i] * sc2);
        } else {   // V transposed: [b,h,hd,n]
          ushort4 pk;
          pk.x = f2bf(c[0]); pk.y = f2bf(c[1]); pk.z = f2bf(c[2]); pk.w = f2bf(c[3]);
          *(ushort4*)(qkv + 2 * Tt + ((size_t)((b * Hh + h) * HDh + hd)) * Nn + n) = pk;
        }
      } else {   // EPI==2: fast gelu -> bf16, two-fragment hid
        ushort* ob = (m0 < 2048) ? (ushort*)outv
                                 : (ushort*)outv2 - (size_t)2048 * N;
        #pragma unroll
        for (int i = 0; i < 4; i++)
          ob[(size_t)(row0 + i) * N + col] = f2bf(gelu_f(c[i]));
      }
    }
  }
}

// ---- wo_ln: fused attn-combine + Wo GEMM + residual + LN2 ------------------
// r22: BM=16, grid 512 = 2 blocks/CU (was 256 = 1/CU). Wave w owns cols
// w*64..w*64+63 of all 16 rows. A-staging/Linv on tid<128 only.
// A = combine(op0..op3)/l (bit-identical order), chunk-XOR involution.
// Epilogue: v = acc + bo + x -> xsk (fp32); 16-row LN -> xn2 bf16.
__global__ __launch_bounds__(256, 2) void wo_ln(
    const ushort* __restrict__ op0, const ushort* __restrict__ op123,
    const float* __restrict__ lp, const ushort* __restrict__ BT,
    const float* __restrict__ bo, const float* __restrict__ x,
    float* __restrict__ xsk, ushort* __restrict__ xn2)
{
  __shared__ __align__(16) ushort As[2][16 * 64];
  __shared__ __align__(16) ushort Bs[2][256 * 64];
  __shared__ float Linv[16][8];
  __shared__ float RS[2][4][16];
  __shared__ float MN[16][2];
  const int tid = threadIdx.x;
  const int wave = tid >> 6, lane = tid & 63;
  const int quad = lane >> 4, l15 = lane & 15;
  const int m0 = blockIdx.x * 16;
  const int srow = lane >> 3, scol = ((lane & 7) ^ srow) * 8;
  int cx[2];
  #pragma unroll
  for (int kk = 0; kk < 2; kk++) cx[kk] = ((kk * 4 + quad) ^ (l15 & 7)) * 8;
  const size_t SPS = (size_t)16 * Nn * HDh;          // op-part stride (ushorts)
  // ---- Linv[r][h] = 1/sum_sp l  (tid<128: r=tid>>3, h=tid&7) ----
  if (tid < 128) {
    const int r = tid >> 3, h = tid & 7;
    const int row = m0 + r;
    const size_t li = (size_t)((row >> 12) * Hh + h) * Nn + (row & (Nn - 1));
    float l = 0.f;
    #pragma unroll
    for (int sp = 0; sp < SPLIT; sp++) l += lp[sp * (16 * Nn) + li];
    Linv[r][h] = 1.0f / l;
  }
  // staging lane mapping for A (tid<128): r=tid>>3 (16 rows), e=tid&7 (chunk)
  const int ar = (tid >> 3) & 15, ae = tid & 7;
  const int ah2 = ae >> 2, ahd0 = (ae & 3) * 8;
  const int arow = m0 + ar;
  const size_t abase = ((size_t)((arow >> 12) * Hh) * Nn + (arow & (Nn - 1))) * HDh + ahd0;
  short8 a0, a1, a2, a3;
  #define LOADA(cs) if (tid < 128) { \
    const size_t off = abase + (size_t)((cs) * 2 + ah2) * (Nn * HDh); \
    a0 = *(const short8*)(op0 + off); \
    a1 = *(const short8*)(op123 + off); \
    a2 = *(const short8*)(op123 + SPS + off); \
    a3 = *(const short8*)(op123 + 2 * SPS + off); }
  #define WRITEA(q, cs) if (tid < 128) { \
    const float inv = Linv[ar][(cs) * 2 + ah2]; \
    short8 w; \
    _Pragma("unroll") \
    for (int j = 0; j < 8; j++) { \
      const float sum = ((bf2f((ushort)a0[j]) + bf2f((ushort)a1[j])) \
                        + bf2f((ushort)a2[j])) + bf2f((ushort)a3[j]); \
      w[j] = (short)f2bf(sum * inv); } \
    *(short8*)(&As[q][ar * 64 + (ae ^ (ar & 7)) * 8]) = w; }
  #define STAGEB(cs, q) { \
    _Pragma("unroll") \
    for (int i = 0; i < 8; i++) \
      gll16(BT + (size_t)(wave * 64 + i * 8 + srow) * 256 + (cs) * 64 + scol, \
            &Bs[q][(wave * 64 + i * 8) * 64]); }
  LOADA(0);
  STAGEB(0, 0);
  __syncthreads();          // Linv visible; Bs[0] drained
  WRITEA(0, 0);
  __syncthreads();          // As[0] ready
  f32x4 acc[4];
  #pragma unroll
  for (int nt = 0; nt < 4; nt++) acc[nt] = (f32x4){0.f,0.f,0.f,0.f};
  int p = 0;
  #pragma unroll
  for (int cs = 0; cs < 4; cs++) {
    if (cs < 3) { LOADA(cs + 1); STAGEB(cs + 1, p ^ 1); }
    #pragma unroll
    for (int kk = 0; kk < 2; kk++) {
      const short8 af = *(const short8*)(&As[p][l15 * 64 + cx[kk]]);
      #pragma unroll
      for (int nt = 0; nt < 4; nt++) {
        const short8 bf = *(const short8*)(&Bs[p][(wave * 64 + nt * 16 + l15) * 64 + cx[kk]]);
        acc[nt] = __builtin_amdgcn_mfma_f32_16x16x32_bf16(af, bf, acc[nt], 0, 0, 0);
      }
    }
    if (cs < 3) WRITEA(p ^ 1, cs + 1);
    __syncthreads();
    p ^= 1;
  }
  // ---- epilogue: v = acc + bo + x ; xsk ; 16-row LN -> xn2 ----
  float v[4][4];
  float s1[4], s2[4];
  #pragma unroll
  for (int i = 0; i < 4; i++) { s1[i] = 0.f; s2[i] = 0.f; }
  const int row0 = m0 + quad * 4;
  #pragma unroll
  for (int nt = 0; nt < 4; nt++) {
    const int col = wave * 64 + nt * 16 + l15;
    const float bv = bo[col];
    #pragma unroll
    for (int i = 0; i < 4; i++) {
      const size_t idx = (size_t)(row0 + i) * Dd + col;
      const float t = (acc[nt][i] + bv) + x[idx];
      v[nt][i] = t;
      xsk[idx] = t;
      s1[i] += t;
      s2[i] += t * t;
    }
  }
  #pragma unroll
  for (int i = 0; i < 4; i++)
    #pragma unroll
    for (int m = 1; m < 16; m <<= 1) {
      s1[i] += __shfl_xor(s1[i], m, 64);
      s2[i] += __shfl_xor(s2[i], m, 64);
    }
  if (l15 == 0) {
    #pragma unroll
    for (int i = 0; i < 4; i++) {
      RS[0][wave][quad * 4 + i] = s1[i];
      RS[1][wave][quad * 4 + i] = s2[i];
    }
  }
  __syncthreads();
  if (tid < 16) {
    const float t1 = RS[0][0][tid] + RS[0][1][tid] + RS[0][2][tid] + RS[0][3][tid];
    const float t2 = RS[1][0][tid] + RS[1][1][tid] + RS[1][2][tid] + RS[1][3][tid];
    const float mean = t1 * (1.0f / Dd);
    float var = t2 * (1.0f / Dd) - mean * mean;
    var = var < 0.f ? 0.f : var;
    MN[tid][0] = mean;
    MN[tid][1] = 1.0f / (sqrtf(var) + 1e-6f);
  }
  __syncthreads();
  #pragma unroll
  for (int i = 0; i < 4; i++) {
    const float mean = MN[quad * 4 + i][0], inv = MN[quad * 4 + i][1];
    #pragma unroll
    for (int nt = 0; nt < 4; nt++) {
      const int col = wave * 64 + nt * 16 + l15;
      xn2[(size_t)(row0 + i) * Dd + col] = f2bf((v[nt][i] - mean) * inv);
    }
  }
  #undef LOADA
  #undef WRITEA
  #undef STAGEB
}

// ---- BMx64-tile MFMA GEMM (W2 only): BK=64 gll16 double-buffer -------------
// A read from two hid fragments (A rows<2048, A2 rows>=2048; blocks never
// straddle since 2048 % BM == 0). r12 chunk-XOR swizzle on As/Bs.
// r22: BM=64 instantiation -> grid (4,128)=512 blocks = 2/CU.
template<int EPI, int BM>
__global__ __launch_bounds__(256, 3) void gemm_epi(
    const ushort* __restrict__ A, const ushort* __restrict__ A2,
    const ushort* __restrict__ BT,
    const float* __restrict__ bias, const float* __restrict__ res,
    void* __restrict__ outv, int N, int K)
{
  constexpr int MI = BM / 64;
  constexpr int AI = BM / 32;
  __shared__ __align__(16) ushort AsF[2][BM * 64 + (BM / 8) * 32];
  __shared__ __align__(16) ushort BsF[2][64 * 64 + 8 * 32];
  const int tid = threadIdx.x;
  const int wave = tid >> 6, lane = tid & 63;
  const int quad = lane >> 4, l15 = lane & 15;
  const int n0 = blockIdx.x * 64, m0 = blockIdx.y * BM;
  const ushort* Abase = (m0 < 2048) ? A : A2 - (size_t)2048 * K;
  f32x4 acc[MI][4];
  #pragma unroll
  for (int mt = 0; mt < MI; mt++)
    #pragma unroll
    for (int nt = 0; nt < 4; nt++) acc[mt][nt] = (f32x4){0.f,0.f,0.f,0.f};
  const int srow = lane >> 3, scol = ((lane & 7) ^ srow) * 8;   // swizzled src chunk
  const ushort* gA[AI];
  #pragma unroll
  for (int ai = 0; ai < AI; ai++)
    gA[ai] = Abase + (size_t)(m0 + ai * 32 + wave * 8 + srow) * K + scol;
  const ushort* gB[2];
  #pragma unroll
  for (int bi = 0; bi < 2; bi++)
    gB[bi] = BT + (size_t)(n0 + bi * 32 + wave * 8 + srow) * K + scol;
  int aoff[MI], boff[4];
  #pragma unroll
  for (int mt = 0; mt < MI; mt++) aoff[mt] = ars(wave * 16 * MI + mt * 16 + l15);
  #pragma unroll
  for (int nt = 0; nt < 4; nt++) boff[nt] = ars(nt * 16 + l15);
  int cx[2];
  #pragma unroll
  for (int kk = 0; kk < 2; kk++) cx[kk] = ((kk * 4 + quad) ^ (l15 & 7)) * 8;
  #pragma unroll
  for (int ai = 0; ai < AI; ai++) gll16(gA[ai], &AsF[0][ars(ai * 32 + wave * 8)]);
  #pragma unroll
  for (int bi = 0; bi < 2; bi++) gll16(gB[bi], &BsF[0][ars(bi * 32 + wave * 8)]);
  __syncthreads();
  const int NC = K >> 6;
  int p = 0;
  for (int c = 0; c < NC; c++) {
    if (c + 1 < NC) {
      #pragma unroll
      for (int ai = 0; ai < AI; ai++)
        gll16(gA[ai] + (c + 1) * 64, &AsF[p ^ 1][ars(ai * 32 + wave * 8)]);
      #pragma unroll
      for (int bi = 0; bi < 2; bi++)
        gll16(gB[bi] + (c + 1) * 64, &BsF[p ^ 1][ars(bi * 32 + wave * 8)]);
    }
    #pragma unroll
    for (int kk = 0; kk < 2; kk++) {
      short8 af[MI];
      #pragma unroll
      for (int mt = 0; mt < MI; mt++)
        af[mt] = *(const short8*)(&AsF[p][aoff[mt] + cx[kk]]);
      #pragma unroll
      for (int nt = 0; nt < 4; nt++) {
        const short8 bf = *(const short8*)(&BsF[p][boff[nt] + cx[kk]]);
        #pragma unroll
        for (int mt = 0; mt < MI; mt++)
          acc[mt][nt] = __builtin_amdgcn_mfma_f32_16x16x32_bf16(af[mt], bf, acc[mt][nt], 0, 0, 0);
      }
    }
    __syncthreads();
    p ^= 1;
  }
  #pragma unroll
  for (int mt = 0; mt < MI; mt++) {
    const int row0 = m0 + wave * (16 * MI) + mt * 16 + quad * 4;
    #pragma unroll
    for (int nt = 0; nt < 4; nt++) {
      const int col = n0 + nt * 16 + l15;
      const float bv = bias[col];
      float c[4];
      #pragma unroll
      for (int i = 0; i < 4; i++) c[i] = acc[mt][nt][i] + bv;
      if (EPI == 1) {
        float* out = (float*)outv;
        #pragma unroll
        for (int i = 0; i < 4; i++) {
          const size_t idx = (size_t)(row0 + i) * N + col;
          out[idx] = c[i] + res[idx];
        }
      } else {
        ushort* out = (ushort*)outv;
        #pragma unroll
        for (int i = 0; i < 4; i++)
          out[(size_t)(row0 + i) * N + col] = f2bf(gelu_f(c[i]));
      }
    }
  }
}

// ---- Flash attention: split-K(4), q=64/wave, bf16 partial O + fp32 l -------
// r12 version (measured ~54-56us, absmax 0.03125). Schraudolph exp2 softmax;
// self-normalizing l. Ks chunk-XOR swizzle; Ps/Vt plain.
__global__ __launch_bounds__(256, 4) void attn_kernel(
    const ushort* __restrict__ qp, const ushort* __restrict__ kp,
    const ushort* __restrict__ vtg, ushort* __restrict__ op0,
    ushort* __restrict__ op123, float* __restrict__ lp)
{
  __shared__ __align__(16) ushort Ks[2][64][32];   // K tile [kv][d] (gll16, chunk-swz)
  __shared__ __align__(16) ushort Vt[2][32][72];   // V^T tile [d][kv] (reg-staged)
  __shared__ __align__(16) ushort Ps[4][64][40];   // per-wave P [q][kv-half]
  const int tid = threadIdx.x;
  const int wave = tid >> 6, lane = tid & 63;
  const int quad = lane >> 4, l15 = lane & 15;
  const int qtb = blockIdx.x, bh = blockIdx.y, sp = blockIdx.z;
  const size_t base = (size_t)bh * Nn * HDh;
  const int q0 = qtb * 256 + wave * 64;
  short8 qf[4];
  #pragma unroll
  for (int qt = 0; qt < 4; qt++)
    qf[qt] = *(const short8*)(qp + base + (size_t)(q0 + qt * 16 + l15) * HDh + quad * 8);
  const int kv0 = sp * KVB;
  const ushort* kg = kp + base + (size_t)(kv0 + wave * 16 + (lane >> 2)) * HDh
                   + (((lane & 3) ^ ((lane >> 3) & 3)) * 8);   // swizzled src chunk
  const int kc = (quad ^ ((l15 >> 1) & 3)) * 8;                // swizzled read chunk
  const int vr = tid >> 3, vc = (tid & 7) * 8;
  const ushort* vg = vtg + base + (size_t)vr * Nn + kv0 + vc;
  ushort* psw = &Ps[wave][0][0];
  f32x4 o[2][4], ol[4];
  #pragma unroll
  for (int qt = 0; qt < 4; qt++) {
    o[0][qt] = (f32x4){0,0,0,0}; o[1][qt] = (f32x4){0,0,0,0};
    ol[qt] = (f32x4){0,0,0,0};
  }
  const short one = (short)0x3F80;
  const short8 ones = {one,one,one,one,one,one,one,one};
  const f32x4 zero4 = {0,0,0,0};
  const float SA = 8388608.0f;        // 2^23
  const float SB = 1065102389.0f;     // (127<<23) - minimax bias (~3% two-sided)
  gll16(kg, &Ks[0][wave * 16][0]);
  int4 vreg = *(const int4*)vg;
  *(int4*)(&Vt[0][vr][vc]) = vreg;
  vreg = *(const int4*)(vg + 64);
  __syncthreads();
  #pragma unroll 2
  for (int step = 0; step < NSTP; step++) {
    const int p = step & 1;
    if (step + 1 < NSTP) {
      gll16(kg + (size_t)(step + 1) * 64 * HDh, &Ks[p ^ 1][wave * 16][0]);
      *(int4*)(&Vt[p ^ 1][vr][vc]) = vreg;
    }
    if (step + 2 < NSTP) vreg = *(const int4*)(vg + (size_t)(step + 2) * 64);
    #pragma unroll
    for (int half = 0; half < 2; half++) {
      #pragma unroll
      for (int nt2 = 0; nt2 < 2; nt2++) {
        const int nt = half * 2 + nt2;
        const short8 kf = *(const short8*)(&Ks[p][nt * 16 + l15][kc]);
        #pragma unroll
        for (int qt = 0; qt < 4; qt++) {
          const f32x4 s = __builtin_amdgcn_mfma_f32_16x16x32_bf16(kf, qf[qt], zero4, 0, 0, 0);
          const unsigned int i0 = (unsigned int)(int)fmaf(s[0], SA, SB);
          const unsigned int i1 = (unsigned int)(int)fmaf(s[1], SA, SB);
          const unsigned int i2 = (unsigned int)(int)fmaf(s[2], SA, SB);
          const unsigned int i3 = (unsigned int)(int)fmaf(s[3], SA, SB);
          uint2 pk;
          pk.x = __builtin_amdgcn_perm(i1, i0, 0x07060302u);
          pk.y = __builtin_amdgcn_perm(i3, i2, 0x07060302u);
          *(uint2*)(psw + (qt * 16 + l15) * 40 + nt2 * 16 + quad * 4) = pk;
        }
      }
      __builtin_amdgcn_wave_barrier();   // Ps wave-local; DS in-order per wave
      const short8 v0 = *(const short8*)(&Vt[p][l15][half * 32 + quad * 8]);
      const short8 v1 = *(const short8*)(&Vt[p][16 + l15][half * 32 + quad * 8]);
      #pragma unroll
      for (int qt = 0; qt < 4; qt++) {
        const short8 pb = *(const short8*)(psw + (qt * 16 + l15) * 40 + quad * 8);
        o[0][qt] = __builtin_amdgcn_mfma_f32_16x16x32_bf16(v0, pb, o[0][qt], 0, 0, 0);
        o[1][qt] = __builtin_amdgcn_mfma_f32_16x16x32_bf16(v1, pb, o[1][qt], 0, 0, 0);
        ol[qt]   = __builtin_amdgcn_mfma_f32_16x16x32_bf16(ones, pb, ol[qt], 0, 0, 0);
      }
      __builtin_amdgcn_wave_barrier();
    }
    __syncthreads();   // drains this step's prefetches (full phase elapsed)
  }
  lp[(size_t)sp * (16 * Nn) + (size_t)bh * Nn + q0 + lane] = ol[lane >> 4][0];
  ushort* ob = (sp == 0 ? op0 : op123 + (size_t)(sp - 1) * (16 * (size_t)Nn * HDh));
  #pragma unroll
  for (int pass = 0; pass < 2; pass++) {
    #pragma unroll
    for (int qt2 = 0; qt2 < 2; qt2++) {
      const int qt = pass * 2 + qt2;
      #pragma unroll
      for (int dt = 0; dt < 2; dt++) {
        ushort4 pk;
        pk.x = f2bf(o[dt][qt][0]); pk.y = f2bf(o[dt][qt][1]);
        pk.z = f2bf(o[dt][qt][2]); pk.w = f2bf(o[dt][qt][3]);
        *(ushort4*)(psw + (qt2 * 16 + l15) * 40 + dt * 16 + quad * 4) = pk;
      }
    }
    __builtin_amdgcn_wave_barrier();
    #pragma unroll
    for (int j = 0; j < 2; j++) {
      const int row = j * 16 + (lane >> 2);
      const short8 ov = *(const short8*)(psw + row * 40 + (lane & 3) * 8);
      const int q = q0 + pass * 32 + row;
      *(short8*)(ob + ((size_t)bh * Nn + q) * HDh + (lane & 3) * 8) = ov;
    }
    __builtin_amdgcn_wave_barrier();
  }
}

extern "C" void kernel_launch(void* const* d_in, const int* in_sizes, int n_in,
                              void* d_out, int out_size, void* d_ws, size_t ws_size,
                              hipStream_t stream)
{
  const float* x  = (const float*)d_in[0];
  const float* Wq = (const float*)d_in[1];
  const float* bq = (const float*)d_in[2];
  const float* Wk = (const float*)d_in[3];
  const float* bk = (const float*)d_in[4];
  const float* Wv = (const float*)d_in[5];
  const float* bv = (const float*)d_in[6];
  const float* Wo = (const float*)d_in[7];
  const float* bo = (const float*)d_in[8];
  const float* W1 = (const float*)d_in[9];
  const float* b1 = (const float*)d_in[10];
  const float* W2 = (const float*)d_in[11];
  const float* b2 = (const float*)d_in[12];

  char* ws = (char*)d_ws;
  ushort* wt    = (ushort*)ws;                       // 786432 bf16
  ushort* wtqkv = wt;
  ushort* wto   = wt + 196608;
  ushort* wt1   = wt + 262144;
  ushort* wt2   = wt + 524288;
  float*  bqkv  = (float*)(ws + 786432 * 2);
  ushort* s0    = (ushort*)(ws + 786432 * 2 + 4096); // 4 MiB slots
  ushort* s1    = s0 + Tt;                           // q (dead after attn)
  ushort* s2    = s1 + Tt;                           // k (dead after attn)
  ushort* s3    = s2 + Tt;                           // v^T (dead after attn)
  ushort* oxsk  = s3 + Tt;                           // old-xsk region (8 MiB)
  ushort* xn1   = s0;
  ushort* op0   = s0;                                // attn partial sp0 (xn1 dead)
  ushort* op123 = oxsk;                              // sp1..sp3 (12 MiB: oxsk+old-xn2)
  float*  xskN  = (float*)s1;                        // fp32 8 MiB (s1+s2)
  ushort* xn2N  = s3;                                // bf16 4 MiB
  ushort* hid1  = s0;                                // hid rows 0..2047
  ushort* hid2  = oxsk;                              // hid rows 2048..8191 (12 MiB)
  float*  lp    = (float*)d_out;                     // scratch in d_out
  float*  outp  = (float*)d_out;

  const dim3 blk(256);
  hipLaunchKernelGGL(p0_kernel, dim3(512), blk, 0, stream,
                     Wq, Wk, Wv, Wo, W1, W2, bq, bk, bv, wt, bqkv, x, xn1);
  hipLaunchKernelGGL((gemm_wide<0>), dim3(6, 64), blk, 0, stream,
                     xn1, wtqkv, bqkv, (void*)s1, 768, Dd, (void*)nullptr);

  hipLaunchKernelGGL(attn_kernel, dim3(Nn / 256, Bb * Hh, SPLIT), blk, 0, stream,
                     s1, s2, s3, op0, op123, lp);

  hipLaunchKernelGGL(wo_ln, dim3(MT / 16), blk, 0, stream,
                     op0, op123, lp, wto, bo, x, xskN, xn2N);

  hipLaunchKernelGGL((gemm_wide<2>), dim3(8, 64), blk, 0, stream,
                     xn2N, wt1, b1, (void*)hid1, DFFd, Dd, (void*)hid2);
  hipLaunchKernelGGL((gemm_epi<1,64>), dim3(4, 128), blk, 0, stream,
                     hid1, hid2, wt2, b2, xskN, (void*)outp, Dd, DFFd);
}

// Round 18
// 179.778 us; speedup vs baseline: 1.0313x; 1.0144x over previous
//
#include <hip/hip_runtime.h>
#include <hip/hip_bf16.h>

// EncoderBlock: B=2, N=4096, D=256, H=8, HD=32, DFF=1024.
// I/O fp32; internal bf16 MFMA.
// r23 (base: r22 = 182.4us best, absmax 0.03125). attn is the largest
// measurable item (54.5us, VALU-bound: VALUBusy 44% > MfmaUtil 31%).
// Single change: Schraudolph pack drops the 4 v_cvt per 4 scores via
// float-add magic WITH Q UNSCALED (isolates the untested half of r13's
// failed bundle): t = fmaf(s,128,2^23+16252); lo16(bits(t)) = bf16 p.
// +-1 ulp (RNE vs trunc) vs verified path; self-normalizing l cancels it.
// PRE-REGISTERED: if absmax > 0.12, float-add-magic is definitively dead
// on this stack; revert to r22 verbatim next round.
// Dead ends: MLP fusion (r18), v_pk_fma asm (r16 NaN), r13 bundle,
// Ps slot-XOR (r14), residency 2->4 (r21 null).
#define Bb 2
#define Nn 4096
#define Dd 256
#define Hh 8
#define HDh 32
#define DFFd 1024
#define MT (Bb*Nn)   // 8192 rows
#define Tt ((size_t)MT * Dd)
#define SPLIT 4
#define KVB (Nn / SPLIT)
#define NSTP (KVB / 64)   // 16

typedef __attribute__((ext_vector_type(8))) short short8;
typedef __attribute__((ext_vector_type(4))) float f32x4;
typedef __attribute__((address_space(1))) const unsigned int gu32;
typedef __attribute__((address_space(3))) unsigned int lu32;

__device__ __forceinline__ void gll16(const ushort* g, ushort* l) {
  // async global->LDS, 16B/lane; LDS dest = wave-uniform base + lane*16
  __builtin_amdgcn_global_load_lds((gu32*)g, (lu32*)l, 16, 0, 0);
}
__device__ __forceinline__ float bf2f(ushort u){
  union { unsigned int i; float f; } v; v.i = ((unsigned int)u) << 16; return v.f;
}
__device__ __forceinline__ ushort f2bf(float f){           // RNE
  union { float f; unsigned int i; } v; v.f = f;
  unsigned int r = v.i + 0x7fffu + ((v.i >> 16) & 1u);
  return (ushort)(r >> 16);
}
__device__ __forceinline__ int ars(int r){ return r * 64 + (r >> 3) * 32; }
__device__ __forceinline__ float gelu_f(float c){
  // gelu_tanh(c) = c*sigmoid(2y), y = 0.79788456(c+0.044715c^3); ~1ulp f32.
  const float u = c * c;
  const float s = __builtin_fmaf(0.044715f * u, c, c);
  const float m = __builtin_amdgcn_exp2f(-2.302144404f * s);
  return c * __builtin_amdgcn_rcpf(1.0f + m);
}

// ---- layernorm helper: 4 rows per wave --------------------------------------
__device__ __forceinline__ void ln_rows4(const float* __restrict__ x,
                                         ushort* __restrict__ out, int row0,
                                         int wave, int lane)
{
  #pragma unroll
  for (int r = 0; r < 4; r++) {
    const int row = row0 + wave * 4 + r;
    const float4 u = *(const float4*)(x + (size_t)row * Dd + lane * 4);
    float s1 = u.x + u.y + u.z + u.w;
    float s2 = u.x*u.x + u.y*u.y + u.z*u.z + u.w*u.w;
    #pragma unroll
    for (int m = 1; m < 64; m <<= 1) { s1 += __shfl_xor(s1, m, 64); s2 += __shfl_xor(s2, m, 64); }
    const float mean = s1 * (1.0f / Dd);
    float var = s2 * (1.0f / Dd) - mean * mean;
    var = var < 0.f ? 0.f : var;
    const float inv = 1.0f / (sqrtf(var) + 1e-6f);
    ushort4 o;
    o.x = f2bf((u.x - mean) * inv); o.y = f2bf((u.y - mean) * inv);
    o.z = f2bf((u.z - mean) * inv); o.w = f2bf((u.w - mean) * inv);
    *(ushort4*)(out + (size_t)row * Dd + lane * 4) = o;
  }
}

// ---- p0: weight transpose prep (blocks 0..192) + LN1 (all 512 blocks) ------
__global__ __launch_bounds__(256) void p0_kernel(
    const float* __restrict__ Wq, const float* __restrict__ Wk,
    const float* __restrict__ Wv, const float* __restrict__ Wo,
    const float* __restrict__ W1, const float* __restrict__ W2,
    const float* __restrict__ bq, const float* __restrict__ bk,
    const float* __restrict__ bv, ushort* __restrict__ wt,
    float* __restrict__ bqkv, const float* __restrict__ x,
    ushort* __restrict__ xn1)
{
  const int bid = blockIdx.x, t = threadIdx.x;
  __shared__ __align__(16) ushort T[64][72];
  if (bid < 192) {
    const float* src; ushort* dst; int Nsrc, Kdst, kt, nt;
    if (bid < 64) {
      const int m = bid >> 4, tile = bid & 15;
      kt = tile >> 2; nt = tile & 3; Nsrc = 256; Kdst = 256;
      src = (m == 0 ? Wq : m == 1 ? Wk : m == 2 ? Wv : Wo);
      dst = (m == 3) ? (wt + 196608) : (wt + m * 65536);
    } else if (bid < 128) {
      const int tile = bid - 64; kt = tile >> 4; nt = tile & 15;
      Nsrc = 1024; Kdst = 256; src = W1; dst = wt + 262144;
    } else {
      const int tile = bid - 128; kt = tile >> 2; nt = tile & 3;
      Nsrc = 256; Kdst = 1024; src = W2; dst = wt + 524288;
    }
    const int k0 = kt * 64, n0 = nt * 64;
    const int cc = t & 15, rr = t >> 4;
    #pragma unroll
    for (int pass = 0; pass < 4; pass++) {
      const int k = rr + pass * 16;
      const float4 v = *(const float4*)(src + (size_t)(k0 + k) * Nsrc + n0 + cc * 4);
      T[cc * 4 + 0][k] = f2bf(v.x); T[cc * 4 + 1][k] = f2bf(v.y);
      T[cc * 4 + 2][k] = f2bf(v.z); T[cc * 4 + 3][k] = f2bf(v.w);
    }
    __syncthreads();
    const int nl = t >> 2, ks = (t & 3) * 16;
    const short8 a = *(const short8*)(&T[nl][ks]);
    const short8 b = *(const short8*)(&T[nl][ks + 8]);
    ushort* drow = dst + (size_t)(n0 + nl) * Kdst + k0 + ks;
    *(short8*)(drow) = a; *(short8*)(drow + 8) = b;
  } else if (bid == 192) {
    bqkv[t] = bq[t]; bqkv[256 + t] = bk[t]; bqkv[512 + t] = bv[t];
  }
  ln_rows4(x, xn1, bid * 16, t >> 6, t & 63);
}

// ---- gemm_wide: 128x128 tile, 4 waves 2x2, per-wave 64x64 acc[4][4] --------
// Single-buffered 32KB LDS + launch_bounds(256,4). Chunk-XOR swizzle.
// EPI==2 (W1) writes hid split across two fragments (outv rows<2048, outv2
// rows>=2048); blocks never straddle (2048 % 128 == 0).
template<int EPI>
__global__ __launch_bounds__(256, 4) void gemm_wide(
    const ushort* __restrict__ A, const ushort* __restrict__ BT,
    const float* __restrict__ bias, void* __restrict__ outv, int N, int K,
    void* __restrict__ outv2)
{
  __shared__ __align__(16) ushort As[128 * 64];
  __shared__ __align__(16) ushort Bs[128 * 64];
  const int tid = threadIdx.x;
  const int wave = tid >> 6, lane = tid & 63;
  const int quad = lane >> 4, l15 = lane & 15;
  const int wm = wave >> 1, wn = wave & 1;
  const int n0 = blockIdx.x * 128, m0 = blockIdx.y * 128;
  f32x4 acc[4][4];
  #pragma unroll
  for (int mt = 0; mt < 4; mt++)
    #pragma unroll
    for (int nt = 0; nt < 4; nt++) acc[mt][nt] = (f32x4){0.f,0.f,0.f,0.f};
  const int srow = lane >> 3, scol = ((lane & 7) ^ srow) * 8;   // swizzled src chunk
  const ushort* gA[4];
  const ushort* gB[4];
  #pragma unroll
  for (int i = 0; i < 4; i++) {
    gA[i] = A  + (size_t)(m0 + i * 32 + wave * 8 + srow) * K + scol;
    gB[i] = BT + (size_t)(n0 + i * 32 + wave * 8 + srow) * K + scol;
  }
  int aoff[4], boff[4], cx[2];
  #pragma unroll
  for (int mt = 0; mt < 4; mt++) aoff[mt] = (wm * 64 + mt * 16 + l15) * 64;
  #pragma unroll
  for (int nt = 0; nt < 4; nt++) boff[nt] = (wn * 64 + nt * 16 + l15) * 64;
  #pragma unroll
  for (int kk = 0; kk < 2; kk++) cx[kk] = ((kk * 4 + quad) ^ (l15 & 7)) * 8;
  const int NC = K >> 6;
  for (int c = 0; c < NC; c++) {
    #pragma unroll
    for (int i = 0; i < 4; i++) {
      gll16(gA[i] + c * 64, &As[(i * 32 + wave * 8) * 64]);
      gll16(gB[i] + c * 64, &Bs[(i * 32 + wave * 8) * 64]);
    }
    __syncthreads();   // drains vmcnt: tile ready
    #pragma unroll
    for (int kk = 0; kk < 2; kk++) {
      short8 af[4];
      #pragma unroll
      for (int mt = 0; mt < 4; mt++)
        af[mt] = *(const short8*)(&As[aoff[mt] + cx[kk]]);
      #pragma unroll
      for (int nt = 0; nt < 4; nt++) {
        const short8 bf = *(const short8*)(&Bs[boff[nt] + cx[kk]]);
        #pragma unroll
        for (int mt = 0; mt < 4; mt++)
          acc[mt][nt] = __builtin_amdgcn_mfma_f32_16x16x32_bf16(af[mt], bf, acc[mt][nt], 0, 0, 0);
      }
    }
    __syncthreads();   // compute done: safe to overwrite tile
  }
  #pragma unroll
  for (int mt = 0; mt < 4; mt++) {
    const int row0 = m0 + wm * 64 + mt * 16 + quad * 4;
    #pragma unroll
    for (int nt = 0; nt < 4; nt++) {
      const int col = n0 + wn * 64 + nt * 16 + l15;
      const float bv = bias[col];
      float c[4];
      #pragma unroll
      for (int i = 0; i < 4; i++) c[i] = acc[mt][nt][i] + bv;
      if (EPI == 0) {
        ushort* qkv = (ushort*)outv;
        const int w = col >> 8, cd = col & 255;
        const int h = cd >> 5, hd = cd & 31;
        const int b = row0 >> 12, n = row0 & (Nn - 1);
        if (w < 2) {
          const float sc2 = (w == 0) ? (1.4426950408889634f * 0.17677669529663687f) : 1.0f;
          ushort* dst = qkv + (size_t)w * Tt + ((size_t)((b * Hh + h) * Nn) + n) * HDh + hd;
          #pragma unroll
          for (int i = 0; i < 4; i++) dst[(size_t)i * HDh] = f2bf(c[i] * sc2);
        } else {   // V transposed: [b,h,hd,n]
          ushort4 pk;
          pk.x = f2bf(c[0]); pk.y = f2bf(c[1]); pk.z = f2bf(c[2]); pk.w = f2bf(c[3]);
          *(ushort4*)(qkv + 2 * Tt + ((size_t)((b * Hh + h) * HDh + hd)) * Nn + n) = pk;
        }
      } else {   // EPI==2: fast gelu -> bf16, two-fragment hid
        ushort* ob = (m0 < 2048) ? (ushort*)outv
                                 : (ushort*)outv2 - (size_t)2048 * N;
        #pragma unroll
        for (int i = 0; i < 4; i++)
          ob[(size_t)(row0 + i) * N + col] = f2bf(gelu_f(c[i]));
      }
    }
  }
}

// ---- wo_ln: fused attn-combine + Wo GEMM + residual + LN2 ------------------
// BM=16, grid 512 = 2 blocks/CU. Wave w owns cols w*64..w*64+63 of all 16
// rows. A-staging/Linv on tid<128 only. A = combine(op0..op3)/l
// (bit-identical order), chunk-XOR involution. Epilogue: v = acc + bo + x
// -> xsk (fp32); 16-row LN -> xn2 bf16.
__global__ __launch_bounds__(256, 2) void wo_ln(
    const ushort* __restrict__ op0, const ushort* __restrict__ op123,
    const float* __restrict__ lp, const ushort* __restrict__ BT,
    const float* __restrict__ bo, const float* __restrict__ x,
    float* __restrict__ xsk, ushort* __restrict__ xn2)
{
  __shared__ __align__(16) ushort As[2][16 * 64];
  __shared__ __align__(16) ushort Bs[2][256 * 64];
  __shared__ float Linv[16][8];
  __shared__ float RS[2][4][16];
  __shared__ float MN[16][2];
  const int tid = threadIdx.x;
  const int wave = tid >> 6, lane = tid & 63;
  const int quad = lane >> 4, l15 = lane & 15;
  const int m0 = blockIdx.x * 16;
  const int srow = lane >> 3, scol = ((lane & 7) ^ srow) * 8;
  int cx[2];
  #pragma unroll
  for (int kk = 0; kk < 2; kk++) cx[kk] = ((kk * 4 + quad) ^ (l15 & 7)) * 8;
  const size_t SPS = (size_t)16 * Nn * HDh;          // op-part stride (ushorts)
  // ---- Linv[r][h] = 1/sum_sp l  (tid<128: r=tid>>3, h=tid&7) ----
  if (tid < 128) {
    const int r = tid >> 3, h = tid & 7;
    const int row = m0 + r;
    const size_t li = (size_t)((row >> 12) * Hh + h) * Nn + (row & (Nn - 1));
    float l = 0.f;
    #pragma unroll
    for (int sp = 0; sp < SPLIT; sp++) l += lp[sp * (16 * Nn) + li];
    Linv[r][h] = 1.0f / l;
  }
  // staging lane mapping for A (tid<128): r=tid>>3 (16 rows), e=tid&7 (chunk)
  const int ar = (tid >> 3) & 15, ae = tid & 7;
  const int ah2 = ae >> 2, ahd0 = (ae & 3) * 8;
  const int arow = m0 + ar;
  const size_t abase = ((size_t)((arow >> 12) * Hh) * Nn + (arow & (Nn - 1))) * HDh + ahd0;
  short8 a0, a1, a2, a3;
  #define LOADA(cs) if (tid < 128) { \
    const size_t off = abase + (size_t)((cs) * 2 + ah2) * (Nn * HDh); \
    a0 = *(const short8*)(op0 + off); \
    a1 = *(const short8*)(op123 + off); \
    a2 = *(const short8*)(op123 + SPS + off); \
    a3 = *(const short8*)(op123 + 2 * SPS + off); }
  #define WRITEA(q, cs) if (tid < 128) { \
    const float inv = Linv[ar][(cs) * 2 + ah2]; \
    short8 w; \
    _Pragma("unroll") \
    for (int j = 0; j < 8; j++) { \
      const float sum = ((bf2f((ushort)a0[j]) + bf2f((ushort)a1[j])) \
                        + bf2f((ushort)a2[j])) + bf2f((ushort)a3[j]); \
      w[j] = (short)f2bf(sum * inv); } \
    *(short8*)(&As[q][ar * 64 + (ae ^ (ar & 7)) * 8]) = w; }
  #define STAGEB(cs, q) { \
    _Pragma("unroll") \
    for (int i = 0; i < 8; i++) \
      gll16(BT + (size_t)(wave * 64 + i * 8 + srow) * 256 + (cs) * 64 + scol, \
            &Bs[q][(wave * 64 + i * 8) * 64]); }
  LOADA(0);
  STAGEB(0, 0);
  __syncthreads();          // Linv visible; Bs[0] drained
  WRITEA(0, 0);
  __syncthreads();          // As[0] ready
  f32x4 acc[4];
  #pragma unroll
  for (int nt = 0; nt < 4; nt++) acc[nt] = (f32x4){0.f,0.f,0.f,0.f};
  int p = 0;
  #pragma unroll
  for (int cs = 0; cs < 4; cs++) {
    if (cs < 3) { LOADA(cs + 1); STAGEB(cs + 1, p ^ 1); }
    #pragma unroll
    for (int kk = 0; kk < 2; kk++) {
      const short8 af = *(const short8*)(&As[p][l15 * 64 + cx[kk]]);
      #pragma unroll
      for (int nt = 0; nt < 4; nt++) {
        const short8 bf = *(const short8*)(&Bs[p][(wave * 64 + nt * 16 + l15) * 64 + cx[kk]]);
        acc[nt] = __builtin_amdgcn_mfma_f32_16x16x32_bf16(af, bf, acc[nt], 0, 0, 0);
      }
    }
    if (cs < 3) WRITEA(p ^ 1, cs + 1);
    __syncthreads();
    p ^= 1;
  }
  // ---- epilogue: v = acc + bo + x ; xsk ; 16-row LN -> xn2 ----
  float v[4][4];
  float s1[4], s2[4];
  #pragma unroll
  for (int i = 0; i < 4; i++) { s1[i] = 0.f; s2[i] = 0.f; }
  const int row0 = m0 + quad * 4;
  #pragma unroll
  for (int nt = 0; nt < 4; nt++) {
    const int col = wave * 64 + nt * 16 + l15;
    const float bv = bo[col];
    #pragma unroll
    for (int i = 0; i < 4; i++) {
      const size_t idx = (size_t)(row0 + i) * Dd + col;
      const float t = (acc[nt][i] + bv) + x[idx];
      v[nt][i] = t;
      xsk[idx] = t;
      s1[i] += t;
      s2[i] += t * t;
    }
  }
  #pragma unroll
  for (int i = 0; i < 4; i++)
    #pragma unroll
    for (int m = 1; m < 16; m <<= 1) {
      s1[i] += __shfl_xor(s1[i], m, 64);
      s2[i] += __shfl_xor(s2[i], m, 64);
    }
  if (l15 == 0) {
    #pragma unroll
    for (int i = 0; i < 4; i++) {
      RS[0][wave][quad * 4 + i] = s1[i];
      RS[1][wave][quad * 4 + i] = s2[i];
    }
  }
  __syncthreads();
  if (tid < 16) {
    const float t1 = RS[0][0][tid] + RS[0][1][tid] + RS[0][2][tid] + RS[0][3][tid];
    const float t2 = RS[1][0][tid] + RS[1][1][tid] + RS[1][2][tid] + RS[1][3][tid];
    const float mean = t1 * (1.0f / Dd);
    float var = t2 * (1.0f / Dd) - mean * mean;
    var = var < 0.f ? 0.f : var;
    MN[tid][0] = mean;
    MN[tid][1] = 1.0f / (sqrtf(var) + 1e-6f);
  }
  __syncthreads();
  #pragma unroll
  for (int i = 0; i < 4; i++) {
    const float mean = MN[quad * 4 + i][0], inv = MN[quad * 4 + i][1];
    #pragma unroll
    for (int nt = 0; nt < 4; nt++) {
      const int col = wave * 64 + nt * 16 + l15;
      xn2[(size_t)(row0 + i) * Dd + col] = f2bf((v[nt][i] - mean) * inv);
    }
  }
  #undef LOADA
  #undef WRITEA
  #undef STAGEB
}

// ---- BMx64-tile MFMA GEMM (W2 only): BK=64 gll16 double-buffer -------------
// A read from two hid fragments (A rows<2048, A2 rows>=2048; blocks never
// straddle since 2048 % BM == 0). r12 chunk-XOR swizzle on As/Bs.
// BM=64 -> grid (4,128)=512 blocks = 2/CU.
template<int EPI, int BM>
__global__ __launch_bounds__(256, 3) void gemm_epi(
    const ushort* __restrict__ A, const ushort* __restrict__ A2,
    const ushort* __restrict__ BT,
    const float* __restrict__ bias, const float* __restrict__ res,
    void* __restrict__ outv, int N, int K)
{
  constexpr int MI = BM / 64;
  constexpr int AI = BM / 32;
  __shared__ __align__(16) ushort AsF[2][BM * 64 + (BM / 8) * 32];
  __shared__ __align__(16) ushort BsF[2][64 * 64 + 8 * 32];
  const int tid = threadIdx.x;
  const int wave = tid >> 6, lane = tid & 63;
  const int quad = lane >> 4, l15 = lane & 15;
  const int n0 = blockIdx.x * 64, m0 = blockIdx.y * BM;
  const ushort* Abase = (m0 < 2048) ? A : A2 - (size_t)2048 * K;
  f32x4 acc[MI][4];
  #pragma unroll
  for (int mt = 0; mt < MI; mt++)
    #pragma unroll
    for (int nt = 0; nt < 4; nt++) acc[mt][nt] = (f32x4){0.f,0.f,0.f,0.f};
  const int srow = lane >> 3, scol = ((lane & 7) ^ srow) * 8;   // swizzled src chunk
  const ushort* gA[AI];
  #pragma unroll
  for (int ai = 0; ai < AI; ai++)
    gA[ai] = Abase + (size_t)(m0 + ai * 32 + wave * 8 + srow) * K + scol;
  const ushort* gB[2];
  #pragma unroll
  for (int bi = 0; bi < 2; bi++)
    gB[bi] = BT + (size_t)(n0 + bi * 32 + wave * 8 + srow) * K + scol;
  int aoff[MI], boff[4];
  #pragma unroll
  for (int mt = 0; mt < MI; mt++) aoff[mt] = ars(wave * 16 * MI + mt * 16 + l15);
  #pragma unroll
  for (int nt = 0; nt < 4; nt++) boff[nt] = ars(nt * 16 + l15);
  int cx[2];
  #pragma unroll
  for (int kk = 0; kk < 2; kk++) cx[kk] = ((kk * 4 + quad) ^ (l15 & 7)) * 8;
  #pragma unroll
  for (int ai = 0; ai < AI; ai++) gll16(gA[ai], &AsF[0][ars(ai * 32 + wave * 8)]);
  #pragma unroll
  for (int bi = 0; bi < 2; bi++) gll16(gB[bi], &BsF[0][ars(bi * 32 + wave * 8)]);
  __syncthreads();
  const int NC = K >> 6;
  int p = 0;
  for (int c = 0; c < NC; c++) {
    if (c + 1 < NC) {
      #pragma unroll
      for (int ai = 0; ai < AI; ai++)
        gll16(gA[ai] + (c + 1) * 64, &AsF[p ^ 1][ars(ai * 32 + wave * 8)]);
      #pragma unroll
      for (int bi = 0; bi < 2; bi++)
        gll16(gB[bi] + (c + 1) * 64, &BsF[p ^ 1][ars(bi * 32 + wave * 8)]);
    }
    #pragma unroll
    for (int kk = 0; kk < 2; kk++) {
      short8 af[MI];
      #pragma unroll
      for (int mt = 0; mt < MI; mt++)
        af[mt] = *(const short8*)(&AsF[p][aoff[mt] + cx[kk]]);
      #pragma unroll
      for (int nt = 0; nt < 4; nt++) {
        const short8 bf = *(const short8*)(&BsF[p][boff[nt] + cx[kk]]);
        #pragma unroll
        for (int mt = 0; mt < MI; mt++)
          acc[mt][nt] = __builtin_amdgcn_mfma_f32_16x16x32_bf16(af[mt], bf, acc[mt][nt], 0, 0, 0);
      }
    }
    __syncthreads();
    p ^= 1;
  }
  #pragma unroll
  for (int mt = 0; mt < MI; mt++) {
    const int row0 = m0 + wave * (16 * MI) + mt * 16 + quad * 4;
    #pragma unroll
    for (int nt = 0; nt < 4; nt++) {
      const int col = n0 + nt * 16 + l15;
      const float bv = bias[col];
      float c[4];
      #pragma unroll
      for (int i = 0; i < 4; i++) c[i] = acc[mt][nt][i] + bv;
      if (EPI == 1) {
        float* out = (float*)outv;
        #pragma unroll
        for (int i = 0; i < 4; i++) {
          const size_t idx = (size_t)(row0 + i) * N + col;
          out[idx] = c[i] + res[idx];
        }
      } else {
        ushort* out = (ushort*)outv;
        #pragma unroll
        for (int i = 0; i < 4; i++)
          out[(size_t)(row0 + i) * N + col] = f2bf(gelu_f(c[i]));
      }
    }
  }
}

// ---- Flash attention: split-K(4), q=64/wave, bf16 partial O + fp32 l -------
// r23: Schraudolph pack via float-add magic, Q UNSCALED:
// t = fmaf(s, 128, 2^23+16252) -> lo16(bits(t)) = 16252 + round(128 s)
// = bf16 p bits (same staircase as verified hi16-trunc path, +-1 ulp).
// Drops 4 v_cvt per 4 scores on the VALU-bound pack. perm lo16 packs 2/uint.
// Self-normalizing l (MFMA-ones) absorbs the ulp jitter.
__global__ __launch_bounds__(256, 4) void attn_kernel(
    const ushort* __restrict__ qp, const ushort* __restrict__ kp,
    const ushort* __restrict__ vtg, ushort* __restrict__ op0,
    ushort* __restrict__ op123, float* __restrict__ lp)
{
  __shared__ __align__(16) ushort Ks[2][64][32];   // K tile [kv][d] (gll16, chunk-swz)
  __shared__ __align__(16) ushort Vt[2][32][72];   // V^T tile [d][kv] (reg-staged)
  __shared__ __align__(16) ushort Ps[4][64][40];   // per-wave P [q][kv-half]
  const int tid = threadIdx.x;
  const int wave = tid >> 6, lane = tid & 63;
  const int quad = lane >> 4, l15 = lane & 15;
  const int qtb = blockIdx.x, bh = blockIdx.y, sp = blockIdx.z;
  const size_t base = (size_t)bh * Nn * HDh;
  const int q0 = qtb * 256 + wave * 64;
  short8 qf[4];
  #pragma unroll
  for (int qt = 0; qt < 4; qt++)
    qf[qt] = *(const short8*)(qp + base + (size_t)(q0 + qt * 16 + l15) * HDh + quad * 8);
  const int kv0 = sp * KVB;
  const ushort* kg = kp + base + (size_t)(kv0 + wave * 16 + (lane >> 2)) * HDh
                   + (((lane & 3) ^ ((lane >> 3) & 3)) * 8);   // swizzled src chunk
  const int kc = (quad ^ ((l15 >> 1) & 3)) * 8;                // swizzled read chunk
  const int vr = tid >> 3, vc = (tid & 7) * 8;
  const ushort* vg = vtg + base + (size_t)vr * Nn + kv0 + vc;
  ushort* psw = &Ps[wave][0][0];
  f32x4 o[2][4], ol[4];
  #pragma unroll
  for (int qt = 0; qt < 4; qt++) {
    o[0][qt] = (f32x4){0,0,0,0}; o[1][qt] = (f32x4){0,0,0,0};
    ol[qt] = (f32x4){0,0,0,0};
  }
  const short one = (short)0x3F80;
  const short8 ones = {one,one,one,one,one,one,one,one};
  const f32x4 zero4 = {0,0,0,0};
  const float SA = 128.0f;
  const float MAGIC = 8404860.0f;     // 2^23 + 16252 (Schraudolph-16 bias)
  gll16(kg, &Ks[0][wave * 16][0]);
  int4 vreg = *(const int4*)vg;
  *(int4*)(&Vt[0][vr][vc]) = vreg;
  vreg = *(const int4*)(vg + 64);
  __syncthreads();
  #pragma unroll 2
  for (int step = 0; step < NSTP; step++) {
    const int p = step & 1;
    if (step + 1 < NSTP) {
      gll16(kg + (size_t)(step + 1) * 64 * HDh, &Ks[p ^ 1][wave * 16][0]);
      *(int4*)(&Vt[p ^ 1][vr][vc]) = vreg;
    }
    if (step + 2 < NSTP) vreg = *(const int4*)(vg + (size_t)(step + 2) * 64);
    #pragma unroll
    for (int half = 0; half < 2; half++) {
      #pragma unroll
      for (int nt2 = 0; nt2 < 2; nt2++) {
        const int nt = half * 2 + nt2;
        const short8 kf = *(const short8*)(&Ks[p][nt * 16 + l15][kc]);
        #pragma unroll
        for (int qt = 0; qt < 4; qt++) {
          const f32x4 s = __builtin_amdgcn_mfma_f32_16x16x32_bf16(kf, qf[qt], zero4, 0, 0, 0);
          const float t0 = __builtin_fmaf(s[0], SA, MAGIC);
          const float t1 = __builtin_fmaf(s[1], SA, MAGIC);
          const float t2 = __builtin_fmaf(s[2], SA, MAGIC);
          const float t3 = __builtin_fmaf(s[3], SA, MAGIC);
          const unsigned int i0 = __builtin_bit_cast(unsigned int, t0);
          const unsigned int i1 = __builtin_bit_cast(unsigned int, t1);
          const unsigned int i2 = __builtin_bit_cast(unsigned int, t2);
          const unsigned int i3 = __builtin_bit_cast(unsigned int, t3);
          uint2 pk;
          pk.x = __builtin_amdgcn_perm(i1, i0, 0x05040100u);
          pk.y = __builtin_amdgcn_perm(i3, i2, 0x05040100u);
          *(uint2*)(psw + (qt * 16 + l15) * 40 + nt2 * 16 + quad * 4) = pk;
        }
      }
      __builtin_amdgcn_wave_barrier();   // Ps wave-local; DS in-order per wave
      const short8 v0 = *(const short8*)(&Vt[p][l15][half * 32 + quad * 8]);
      const short8 v1 = *(const short8*)(&Vt[p][16 + l15][half * 32 + quad * 8]);
      #pragma unroll
      for (int qt = 0; qt < 4; qt++) {
        const short8 pb = *(const short8*)(psw + (qt * 16 + l15) * 40 + quad * 8);
        o[0][qt] = __builtin_amdgcn_mfma_f32_16x16x32_bf16(v0, pb, o[0][qt], 0, 0, 0);
        o[1][qt] = __builtin_amdgcn_mfma_f32_16x16x32_bf16(v1, pb, o[1][qt], 0, 0, 0);
        ol[qt]   = __builtin_amdgcn_mfma_f32_16x16x32_bf16(ones, pb, ol[qt], 0, 0, 0);
      }
      __builtin_amdgcn_wave_barrier();
    }
    __syncthreads();   // drains this step's prefetches (full phase elapsed)
  }
  lp[(size_t)sp * (16 * Nn) + (size_t)bh * Nn + q0 + lane] = ol[lane >> 4][0];
  ushort* ob = (sp == 0 ? op0 : op123 + (size_t)(sp - 1) * (16 * (size_t)Nn * HDh));
  #pragma unroll
  for (int pass = 0; pass < 2; pass++) {
    #pragma unroll
    for (int qt2 = 0; qt2 < 2; qt2++) {
      const int qt = pass * 2 + qt2;
      #pragma unroll
      for (int dt = 0; dt < 2; dt++) {
        ushort4 pk;
        pk.x = f2bf(o[dt][qt][0]); pk.y = f2bf(o[dt][qt][1]);
        pk.z = f2bf(o[dt][qt][2]); pk.w = f2bf(o[dt][qt][3]);
        *(ushort4*)(psw + (qt2 * 16 + l15) * 40 + dt * 16 + quad * 4) = pk;
      }
    }
    __builtin_amdgcn_wave_barrier();
    #pragma unroll
    for (int j = 0; j < 2; j++) {
      const int row = j * 16 + (lane >> 2);
      const short8 ov = *(const short8*)(psw + row * 40 + (lane & 3) * 8);
      const int q = q0 + pass * 32 + row;
      *(short8*)(ob + ((size_t)bh * Nn + q) * HDh + (lane & 3) * 8) = ov;
    }
    __builtin_amdgcn_wave_barrier();
  }
}

extern "C" void kernel_launch(void* const* d_in, const int* in_sizes, int n_in,
                              void* d_out, int out_size, void* d_ws, size_t ws_size,
                              hipStream_t stream)
{
  const float* x  = (const float*)d_in[0];
  const float* Wq = (const float*)d_in[1];
  const float* bq = (const float*)d_in[2];
  const float* Wk = (const float*)d_in[3];
  const float* bk = (const float*)d_in[4];
  const float* Wv = (const float*)d_in[5];
  const float* bv = (const float*)d_in[6];
  const float* Wo = (const float*)d_in[7];
  const float* bo = (const float*)d_in[8];
  const float* W1 = (const float*)d_in[9];
  const float* b1 = (const float*)d_in[10];
  const float* W2 = (const float*)d_in[11];
  const float* b2 = (const float*)d_in[12];

  char* ws = (char*)d_ws;
  ushort* wt    = (ushort*)ws;                       // 786432 bf16
  ushort* wtqkv = wt;
  ushort* wto   = wt + 196608;
  ushort* wt1   = wt + 262144;
  ushort* wt2   = wt + 524288;
  float*  bqkv  = (float*)(ws + 786432 * 2);
  ushort* s0    = (ushort*)(ws + 786432 * 2 + 4096); // 4 MiB slots
  ushort* s1    = s0 + Tt;                           // q (dead after attn)
  ushort* s2    = s1 + Tt;                           // k (dead after attn)
  ushort* s3    = s2 + Tt;                           // v^T (dead after attn)
  ushort* oxsk  = s3 + Tt;                           // old-xsk region (8 MiB)
  ushort* xn1   = s0;
  ushort* op0   = s0;                                // attn partial sp0 (xn1 dead)
  ushort* op123 = oxsk;                              // sp1..sp3 (12 MiB: oxsk+old-xn2)
  float*  xskN  = (float*)s1;                        // fp32 8 MiB (s1+s2)
  ushort* xn2N  = s3;                                // bf16 4 MiB
  ushort* hid1  = s0;                                // hid rows 0..2047
  ushort* hid2  = oxsk;                              // hid rows 2048..8191 (12 MiB)
  float*  lp    = (float*)d_out;                     // scratch in d_out
  float*  outp  = (float*)d_out;

  const dim3 blk(256);
  hipLaunchKernelGGL(p0_kernel, dim3(512), blk, 0, stream,
                     Wq, Wk, Wv, Wo, W1, W2, bq, bk, bv, wt, bqkv, x, xn1);
  hipLaunchKernelGGL((gemm_wide<0>), dim3(6, 64), blk, 0, stream,
                     xn1, wtqkv, bqkv, (void*)s1, 768, Dd, (void*)nullptr);

  hipLaunchKernelGGL(attn_kernel, dim3(Nn / 256, Bb * Hh, SPLIT), blk, 0, stream,
                     s1, s2, s3, op0, op123, lp);

  hipLaunchKernelGGL(wo_ln, dim3(MT / 16), blk, 0, stream,
                     op0, op123, lp, wto, bo, x, xskN, xn2N);

  hipLaunchKernelGGL((gemm_wide<2>), dim3(8, 64), blk, 0, stream,
                     xn2N, wt1, b1, (void*)hid1, DFFd, Dd, (void*)hid2);
  hipLaunchKernelGGL((gemm_epi<1,64>), dim3(4, 128), blk, 0, stream,
                     hid1, hid2, wt2, b2, xskN, (void*)outp, Dd, DFFd);
}